// Round 5
// baseline (656.660 us; speedup 1.0000x reference)
//
#include <hip/hip_runtime.h>
#include <hip/hip_bf16.h>

#define BB 16
#define LL 256
#define DD 256
#define DI 512
#define DS 16

typedef __attribute__((ext_vector_type(8))) short bf16x8;
typedef __attribute__((ext_vector_type(4))) float f32x4;

__device__ inline short f2bf(float f) {
    __hip_bfloat16 h = __float2bfloat16(f);
    return *reinterpret_cast<short*>(&h);
}
__device__ inline float bf2f_s(short s) {
    __hip_bfloat16 h = *reinterpret_cast<__hip_bfloat16*>(&s);
    return __bfloat162float(h);
}
__device__ inline void stf(float* p, float v) { *p = v; }
__device__ inline void stf(__hip_bfloat16* p, float v) { *p = __float2bfloat16(v); }

// ---------------- patch embed: h[b,l,d], 256 blocks ----------------
__global__ __launch_bounds__(256) void patch_embed(const float* __restrict__ x,
                                                   const float* __restrict__ pw,
                                                   const float* __restrict__ pb,
                                                   float* __restrict__ h) {
    int blk = blockIdx.x;           // b*16 + lg
    int b = blk >> 4, lg = blk & 15;
    int tid = threadIdx.x;
    __shared__ float pws[48 * 258];  // transposed, padded
    __shared__ float xs[16][48];
    for (int it = 0; it < 48; ++it) {
        int idx = tid + it * 256;    // 12288 total
        float v = pw[idx];
        int dd = idx / 48, k = idx - dd * 48;
        pws[k * 258 + dd] = v;
    }
    for (int idx = tid; idx < 16 * 48; idx += 256) {
        int li = idx / 48, k = idx - li * 48;
        int c = k >> 4, py = (k >> 2) & 3, px = k & 3;
        xs[li][k] = x[(size_t)(b * 3 + c) * 4096 + (lg * 4 + py) * 64 + li * 4 + px];
    }
    __syncthreads();
    float bv = pb[tid];
#pragma unroll 4
    for (int li = 0; li < 16; ++li) {
        float acc = bv;
#pragma unroll
        for (int k = 0; k < 48; ++k) acc += xs[li][k] * pws[k * 258 + tid];
        h[((size_t)(b * 256 + lg * 16 + li)) * 256 + tid] = acc;
    }
}

// ---------------- time embedding ----------------
__global__ void time_embed(const int* __restrict__ t, const float* __restrict__ tw1,
                           const float* __restrict__ tb1, const float* __restrict__ tw2,
                           const float* __restrict__ tb2, float* __restrict__ te) {
    int b = blockIdx.x, j = threadIdx.x;
    __shared__ float s0[256], s1[256];
    float tv = (float)t[b];
    if (j < 128) {
        float f = expf((float)j * (-9.210340371976184f / 127.f));
        float a = tv * f;
        s0[j] = sinf(a);
        s0[j + 128] = cosf(a);
    }
    __syncthreads();
    float acc = tb1[j];
    for (int k = 0; k < 256; ++k) acc += s0[k] * tw1[j * 256 + k];
    s1[j] = acc / (1.f + expf(-acc));
    __syncthreads();
    float acc2 = tb2[j];
    for (int k = 0; k < 256; ++k) acc2 += s1[k] * tw2[j * 256 + k];
    te[b * 256 + j] = acc2;
}

// ---------------- layernorm (optionally + te), templated output ----------------
template <typename TO>
__global__ void ln_kernel(const float* __restrict__ h, const float* __restrict__ te,
                          const float* __restrict__ g, const float* __restrict__ bta,
                          TO* __restrict__ out) {
    int row = blockIdx.x;         // b*L + l
    int b = row >> 8;
    int d = threadIdx.x;
    float v = h[(size_t)row * 256 + d] + (te ? te[b * 256 + d] : 0.f);
    float s = v, s2 = v * v;
#pragma unroll
    for (int o = 32; o; o >>= 1) {
        s += __shfl_down(s, o, 64);
        s2 += __shfl_down(s2, o, 64);
    }
    __shared__ float ws[4], ws2[4];
    int wid = threadIdx.x >> 6, lane = threadIdx.x & 63;
    if (lane == 0) { ws[wid] = s; ws2[wid] = s2; }
    __syncthreads();
    float mu = (ws[0] + ws[1] + ws[2] + ws[3]) * (1.f / 256.f);
    float m2 = (ws2[0] + ws2[1] + ws2[2] + ws2[3]) * (1.f / 256.f);
    float var = m2 - mu * mu;
    stf(&out[(size_t)row * 256 + d], (v - mu) * rsqrtf(var + 1e-5f) * g[d] + bta[d]);
}

// ---------------- bf16 MFMA GEMM ----------------
// C[M,N] (+)= act(A[M,K] @ W[N,K]^T + bias).  Generic BM; 4 waves (WM x WN).
// AMODE: 0 = A bf16 (lda stride), 1 = A fp32 (lda stride), 2 = gate-fuse:
//        A = y2 bf16 [M][1024], A2 = xz bf16 [M][1024]; a[row][j] = (yf+yb)*silu(z).
// OBF: write C as bf16 (else fp32; ADD only with fp32).
// Dual mode (nsplit>0): block-columns with n0>=nsplit use {A2,W2,bias2}.
template <int BM, int BN, int WM, int WN, int FM, int FN, int ACT, bool ADD,
          bool HASBIAS, int AMODE, bool OBF>
__global__ __launch_bounds__(256) void gemm_mfma(
    const void* __restrict__ Ap, const float* __restrict__ W,
    const float* __restrict__ bias, void* __restrict__ Cp,
    int M, int N, int K, int lda,
    const void* __restrict__ A2p, const float* __restrict__ W2,
    const float* __restrict__ bias2, int nsplit)
{
    constexpr int LDP = 40;   // padded bf16 elems per LDS row
    __shared__ __align__(16) short As[BM * LDP];
    __shared__ __align__(16) short Ws[BN * LDP];
    int tid = threadIdx.x;
    int lane = tid & 63;
    int w = tid >> 6;
    int wm, wn;
    if (WN == 1) { wm = w; wn = 0; } else { wm = w >> 1; wn = w & 1; }
    int m0 = blockIdx.y * BM;
    int n0 = blockIdx.x * BN;
    int wn0 = n0;
    if (nsplit > 0 && n0 >= nsplit) { Ap = A2p; W = W2; bias = bias2; wn0 = n0 - nsplit; }

    f32x4 acc[FM][FN];
#pragma unroll
    for (int i = 0; i < FM; ++i)
#pragma unroll
        for (int j = 0; j < FN; ++j) acc[i][j] = (f32x4){0.f, 0.f, 0.f, 0.f};

    for (int k0 = 0; k0 < K; k0 += 32) {
        // ---- stage A tile (BMx32 bf16) ----
        if (AMODE == 0) {
            for (int idx = tid; idx < BM * 4; idx += 256) {
                int row = idx >> 2, qc = idx & 3;
                const __hip_bfloat16* g = (const __hip_bfloat16*)Ap +
                    (size_t)(m0 + row) * lda + k0 + qc * 8;
                *(bf16x8*)&As[row * LDP + qc * 8] = *(const bf16x8*)g;
            }
        } else if (AMODE == 1) {
            for (int idx = tid; idx < BM * 4; idx += 256) {
                int row = idx >> 2, qc = idx & 3;
                const float* g = (const float*)Ap + (size_t)(m0 + row) * lda + k0 + qc * 8;
                float4 v0 = *(const float4*)g;
                float4 v1 = *(const float4*)(g + 4);
                union { bf16x8 v; short s[8]; } u8;
                u8.s[0] = f2bf(v0.x); u8.s[1] = f2bf(v0.y); u8.s[2] = f2bf(v0.z); u8.s[3] = f2bf(v0.w);
                u8.s[4] = f2bf(v1.x); u8.s[5] = f2bf(v1.y); u8.s[6] = f2bf(v1.z); u8.s[7] = f2bf(v1.w);
                *(bf16x8*)&As[row * LDP + qc * 8] = u8.v;
            }
        } else {
            for (int idx = tid; idx < BM * 4; idx += 256) {
                int row = idx >> 2, qc = idx & 3;
                size_t rb = (size_t)(m0 + row) * 1024 + k0 + qc * 8;
                union { bf16x8 v; short s[8]; } uf, ub, uz, r;
                uf.v = *(const bf16x8*)((const __hip_bfloat16*)Ap + rb);
                ub.v = *(const bf16x8*)((const __hip_bfloat16*)Ap + rb + 512);
                uz.v = *(const bf16x8*)((const __hip_bfloat16*)A2p + rb + 512);
#pragma unroll
                for (int e = 0; e < 8; ++e) {
                    float z = bf2f_s(uz.s[e]);
                    float sg = z / (1.f + __expf(-z));
                    r.s[e] = f2bf((bf2f_s(uf.s[e]) + bf2f_s(ub.s[e])) * sg);
                }
                *(bf16x8*)&As[row * LDP + qc * 8] = r.v;
            }
        }
        // ---- stage W tile (BNx32, fp32 -> bf16) ----
        for (int idx = tid; idx < BN * 4; idx += 256) {
            int row = idx >> 2, qc = idx & 3;
            const float* g = W + (size_t)(wn0 + row) * K + k0 + qc * 8;
            float4 v0 = *(const float4*)g;
            float4 v1 = *(const float4*)(g + 4);
            union { bf16x8 v; short s[8]; } u8;
            u8.s[0] = f2bf(v0.x); u8.s[1] = f2bf(v0.y); u8.s[2] = f2bf(v0.z); u8.s[3] = f2bf(v0.w);
            u8.s[4] = f2bf(v1.x); u8.s[5] = f2bf(v1.y); u8.s[6] = f2bf(v1.z); u8.s[7] = f2bf(v1.w);
            *(bf16x8*)&Ws[row * LDP + qc * 8] = u8.v;
        }
        __syncthreads();
        int kg = lane >> 4, r = lane & 15;
        bf16x8 af[FM], bfr[FN];
#pragma unroll
        for (int i = 0; i < FM; ++i)
            af[i] = *(const bf16x8*)&As[(wm * FM * 16 + i * 16 + r) * LDP + kg * 8];
#pragma unroll
        for (int j = 0; j < FN; ++j)
            bfr[j] = *(const bf16x8*)&Ws[(wn * FN * 16 + j * 16 + r) * LDP + kg * 8];
#pragma unroll
        for (int i = 0; i < FM; ++i)
#pragma unroll
            for (int j = 0; j < FN; ++j)
                acc[i][j] = __builtin_amdgcn_mfma_f32_16x16x32_bf16(af[i], bfr[j], acc[i][j], 0, 0, 0);
        __syncthreads();
    }
    // epilogue: C row=(lane>>4)*4+reg, col=lane&15
    int r = lane & 15, qg = lane >> 4;
#pragma unroll
    for (int i = 0; i < FM; ++i) {
#pragma unroll
        for (int j = 0; j < FN; ++j) {
            int col = n0 + wn * FN * 16 + j * 16 + r;
            int colw = wn0 + wn * FN * 16 + j * 16 + r;
            float bv = HASBIAS ? bias[colw] : 0.f;
#pragma unroll
            for (int q = 0; q < 4; ++q) {
                int rowm = m0 + wm * FM * 16 + i * 16 + qg * 4 + q;
                float v = acc[i][j][q] + bv;
                if (ACT == 1) v = (v > 20.f) ? v : log1pf(__expf(v));
                size_t o = (size_t)rowm * N + col;
                if (OBF) ((__hip_bfloat16*)Cp)[o] = __float2bfloat16(v);
                else if (ADD) ((float*)Cp)[o] += v;
                else ((float*)Cp)[o] = v;
            }
        }
    }
}

// ---------------- fp32 GEMM for the small head ----------------
template <int ACT, bool ADD, bool HASBIAS>
__global__ __launch_bounds__(256) void gemm_nt(const float* __restrict__ A,
                                               const float* __restrict__ W,
                                               const float* __restrict__ bias,
                                               float* __restrict__ C,
                                               int M, int N, int K, int lda) {
    __shared__ float Asm[16][65];
    __shared__ float Wsm[16][65];
    int tx = threadIdx.x & 15, ty = threadIdx.x >> 4;
    int m0 = blockIdx.y * 64, n0 = blockIdx.x * 64;
    float acc[4][4] = {};
    for (int k0 = 0; k0 < K; k0 += 16) {
#pragma unroll
        for (int i = 0; i < 4; ++i) {
            int idx = threadIdx.x + i * 256;
            int rr = idx >> 4, cc = idx & 15;
            Asm[cc][rr] = A[(size_t)(m0 + rr) * lda + k0 + cc];
            int n = n0 + rr;
            Wsm[cc][rr] = (n < N) ? W[(size_t)n * K + k0 + cc] : 0.f;
        }
        __syncthreads();
#pragma unroll
        for (int k = 0; k < 16; ++k) {
            float av[4], wv[4];
#pragma unroll
            for (int i = 0; i < 4; ++i) av[i] = Asm[k][ty * 4 + i];
#pragma unroll
            for (int j = 0; j < 4; ++j) wv[j] = Wsm[k][tx * 4 + j];
#pragma unroll
            for (int i = 0; i < 4; ++i)
#pragma unroll
                for (int j = 0; j < 4; ++j) acc[i][j] += av[i] * wv[j];
        }
        __syncthreads();
    }
#pragma unroll
    for (int i = 0; i < 4; ++i) {
        int m = m0 + ty * 4 + i;
#pragma unroll
        for (int j = 0; j < 4; ++j) {
            int n = n0 + tx * 4 + j;
            if (n < N) {
                float v = acc[i][j];
                if (HASBIAS) v += bias[n];
                if (ADD) C[(size_t)m * N + n] += v;
                else C[(size_t)m * N + n] = v;
            }
        }
    }
}

// ---------------- causal depthwise conv (k=4) + silu, vectorized bf16x8 ----------------
__global__ __launch_bounds__(256) void conv_silu(
    const __hip_bfloat16* __restrict__ xz, const float* __restrict__ cw,
    const float* __restrict__ cb, __hip_bfloat16* __restrict__ u) {
    int g = blockIdx.x * 4 + (threadIdx.x >> 6);   // row index b*L + l
    int lane = threadIdx.x & 63;
    int l = g & 255;
    int d0 = lane * 8;
    const __hip_bfloat16* base = xz + (size_t)g * 1024 + d0;
    union { bf16x8 v; short s[8]; } t0, t1, t2, t3, r;
    bf16x8 zz = {};
    t3.v = *(const bf16x8*)base;
    t2.v = (l >= 1) ? *(const bf16x8*)(base - 1024) : zz;
    t1.v = (l >= 2) ? *(const bf16x8*)(base - 2048) : zz;
    t0.v = (l >= 3) ? *(const bf16x8*)(base - 3072) : zz;
#pragma unroll
    for (int e = 0; e < 8; ++e) {
        int d = d0 + e;
        const float4 wv = *(const float4*)(cw + d * 4);
        float acc = cb[d] + bf2f_s(t0.s[e]) * wv.x + bf2f_s(t1.s[e]) * wv.y +
                    bf2f_s(t2.s[e]) * wv.z + bf2f_s(t3.s[e]) * wv.w;
        r.s[e] = f2bf(acc / (1.f + __expf(-acc)));
    }
    *(bf16x8*)(u + (size_t)g * 512 + d0) = r.v;
}

// ================= fused chunked SSM scan v3 =================
// grid = 1024: blk = ((b*2+dir)*32 + dg), dg selects 16 channels.
// 256 threads = 16 chunks (cc=tid>>4) x 16 channels (dl=tid&15); chunk len 16.
// LDS 50 KB -> 3 blocks/CU (12 waves).
__global__ __launch_bounds__(256) void scan_fused(
    const __hip_bfloat16* __restrict__ u, const __hip_bfloat16* __restrict__ dt2,
    const float* __restrict__ pf2,
    const float* __restrict__ Alog_f, const float* __restrict__ Alog_b,
    const float* __restrict__ Dv_f, const float* __restrict__ Dv_b,
    __hip_bfloat16* __restrict__ y2)
{
    int blk = blockIdx.x;
    int dg = blk & 31;
    int bd = blk >> 5;
    int dir = bd & 1, b = bd >> 1;
    int tid = threadIdx.x;
    int dl = tid & 15, cc = tid >> 4;
    int d = dg * 16 + dl;
    int poff = dir ? 64 : 0;
    int doff = dir ? 512 : 0;
    const float* Alog = dir ? Alog_b : Alog_f;
    float Dval = (dir ? Dv_b : Dv_f)[d];

    __shared__ short Bs[256][18];   // bf16, padded (bank-safe for 16-row strides)
    __shared__ short Cs[256][18];
    __shared__ float Ps[16][16][16];
    __shared__ float Fs[16][16][16];

    for (int idx = tid; idx < 4096; idx += 256) {
        int i = idx >> 4, s = idx & 15;
        int tt = dir ? 255 - i : i;
        const float* pr = pf2 + ((size_t)b * 256 + tt) * 128 + poff;
        Bs[i][s] = f2bf(pr[32 + s]);
        Cs[i][s] = f2bf(pr[48 + s]);
    }
    float A2[16];                    // -exp(Alog) * log2(e)  (for exp2f)
    {
        const float* ap = Alog + d * 16;
#pragma unroll
        for (int s = 0; s < 16; ++s) A2[s] = -__expf(ap[s]) * 1.44269504f;
    }
    __syncthreads();

    int i0 = cc * 16;
    int row0 = b * 256 + (dir ? 255 - i0 : i0);
    int stp = dir ? -1 : 1;
    const __hip_bfloat16* dtp = dt2 + (size_t)row0 * 1024 + doff + d;
    const __hip_bfloat16* up  = u  + (size_t)row0 * 512 + d;

    float h[16];
#pragma unroll
    for (int s = 0; s < 16; ++s) h[s] = 0.f;
    float S = 0.f;
#pragma unroll 4
    for (int k = 0; k < 16; ++k) {
        float dtv = __bfloat162float(dtp[(k * stp) * 1024]);
        float uv  = __bfloat162float(up[(k * stp) * 512]);
        S += dtv;
        float du = dtv * uv;
        int i = i0 + k;
#pragma unroll
        for (int s = 0; s < 16; ++s)
            h[s] = exp2f(dtv * A2[s]) * h[s] + du * bf2f_s(Bs[i][s]);
    }
#pragma unroll
    for (int s = 0; s < 16; ++s) {
        Ps[s][cc][dl] = exp2f(A2[s] * S);
        Fs[s][cc][dl] = h[s];
    }
    __syncthreads();
    {   // prefix over 16 chunks: 256 (s,ch) pairs, 1 per thread
        int s2 = tid >> 4, dl2 = tid & 15;
        float hh = 0.f;
#pragma unroll
        for (int c2 = 0; c2 < 16; ++c2) {
            float pv = Ps[s2][c2][dl2];
            float fv = Fs[s2][c2][dl2];
            Ps[s2][c2][dl2] = hh;       // Hin for chunk c2
            hh = fv + pv * hh;
        }
    }
    __syncthreads();
#pragma unroll
    for (int s = 0; s < 16; ++s) h[s] = Ps[s][cc][dl];
    __hip_bfloat16* yp = y2 + (size_t)row0 * 1024 + doff + d;
#pragma unroll 4
    for (int k = 0; k < 16; ++k) {
        float dtv = __bfloat162float(dtp[(k * stp) * 1024]);
        float uv  = __bfloat162float(up[(k * stp) * 512]);
        float du = dtv * uv;
        float acc = 0.f;
        int i = i0 + k;
#pragma unroll
        for (int s = 0; s < 16; ++s) {
            h[s] = exp2f(dtv * A2[s]) * h[s] + du * bf2f_s(Bs[i][s]);
            acc += h[s] * bf2f_s(Cs[i][s]);
        }
        yp[(k * stp) * 1024] = __float2bfloat16(acc + uv * Dval);
    }
}

// ---------------- unpatchify ----------------
__global__ void unpatch(const float* __restrict__ tmp, float* __restrict__ out) {
    int i = blockIdx.x * blockDim.x + threadIdx.x;
    if (i >= 16 * 3 * 64 * 64) return;
    int b = i / (3 * 4096);
    int rem = i % (3 * 4096);
    int c = rem / 4096;
    int pos = rem % 4096;
    int hy = pos >> 6, wx = pos & 63;
    int l = (hy >> 2) * 16 + (wx >> 2);
    int jj = c * 16 + (hy & 3) * 4 + (wx & 3);
    out[i] = tmp[((size_t)b * 256 + l) * 48 + jj];
}

extern "C" void kernel_launch(void* const* d_in, const int* in_sizes, int n_in,
                              void* d_out, int out_size, void* d_ws, size_t ws_size,
                              hipStream_t stream) {
    const float* x        = (const float*)d_in[0];
    const int*   t        = (const int*)d_in[1];
    const float* patch_w  = (const float*)d_in[2];
    const float* patch_b  = (const float*)d_in[3];
    const float* tw1      = (const float*)d_in[4];
    const float* tb1      = (const float*)d_in[5];
    const float* tw2      = (const float*)d_in[6];
    const float* tb2      = (const float*)d_in[7];
    const float* norm_g   = (const float*)d_in[8];
    const float* norm_b   = (const float*)d_in[9];
    const float* inproj_w = (const float*)d_in[10];
    const float* conv_w   = (const float*)d_in[11];
    const float* conv_b   = (const float*)d_in[12];
    const float* Alog_f   = (const float*)d_in[13];
    const float* D_f      = (const float*)d_in[14];
    const float* xproj_f  = (const float*)d_in[15];
    const float* dtw_f    = (const float*)d_in[16];
    const float* dtb_f    = (const float*)d_in[17];
    const float* Alog_bk  = (const float*)d_in[18];
    const float* D_bk     = (const float*)d_in[19];
    const float* xproj_bk = (const float*)d_in[20];
    const float* dtw_bk   = (const float*)d_in[21];
    const float* dtb_bk   = (const float*)d_in[22];
    const float* outproj_w= (const float*)d_in[23];
    const float* fng      = (const float*)d_in[24];
    const float* fnb      = (const float*)d_in[25];
    const float* fin_w    = (const float*)d_in[26];
    const float* fin_b    = (const float*)d_in[27];
    float* out = (float*)d_out;

    char* base = (char*)d_ws;
    float*          te  = (float*)base;                                   // 16 KB
    float*          h   = (float*)(base + (16UL << 10));                  // 4 MB
    __hip_bfloat16* hn  = (__hip_bfloat16*)(base + (16UL << 10) + (4UL << 20));   // 2 MB
    __hip_bfloat16* xz  = (__hip_bfloat16*)((char*)hn + (2UL << 20));     // 8 MB
    __hip_bfloat16* uu  = (__hip_bfloat16*)((char*)xz + (8UL << 20));     // 4 MB
    float*          pf2 = (float*)((char*)uu + (4UL << 20));              // 2 MB
    __hip_bfloat16* dt2 = (__hip_bfloat16*)((char*)pf2 + (2UL << 20));    // 8 MB
    __hip_bfloat16* y2  = (__hip_bfloat16*)((char*)dt2 + (8UL << 20));    // 8 MB
    float*          hnf = (float*)dt2;   // reuse after last scan
    float*          htmp= pf2;           // head tmp reuse

    const int M = BB * LL;                // 4096

    patch_embed<<<256, 256, 0, stream>>>(x, patch_w, patch_b, h);
    time_embed<<<BB, 256, 0, stream>>>(t, tw1, tb1, tw2, tb2, te);

    for (int i = 0; i < 4; ++i) {
        ln_kernel<__hip_bfloat16><<<M, 256, 0, stream>>>(
            h, te, norm_g + i * 256, norm_b + i * 256, hn);
        // inproj: xz[4096,1024] = hn @ W^T   (bf16 out)
        gemm_mfma<128, 128, 2, 2, 4, 4, 0, false, false, 0, true><<<dim3(8, 32), 256, 0, stream>>>(
            hn, inproj_w + (size_t)i * 1024 * 256, nullptr, xz, M, 1024, 256, 256,
            nullptr, nullptr, nullptr, 0);
        conv_silu<<<1024, 256, 0, stream>>>(xz, conv_w + i * 2048, conv_b + i * 512, uu);
        // fused xproj f|b: pf2[4096,128]  (fp32 out)
        gemm_mfma<32, 64, 2, 2, 1, 2, 0, false, false, 0, false><<<dim3(2, 128), 256, 0, stream>>>(
            uu, xproj_f + (size_t)i * 64 * 512, nullptr, pf2, M, 128, 512, 512,
            uu, xproj_bk + (size_t)i * 64 * 512, nullptr, 64);
        // fused dt f|b: dt2[4096,1024] = softplus(pf2[:, dtp] @ dtw^T + dtb)  (bf16 out)
        gemm_mfma<128, 128, 2, 2, 4, 4, 1, false, true, 1, true><<<dim3(8, 32), 256, 0, stream>>>(
            pf2, dtw_f + (size_t)i * 512 * 32, dtb_f + i * 512, dt2, M, 1024, 32, 128,
            pf2 + 64, dtw_bk + (size_t)i * 512 * 32, dtb_bk + i * 512, 512);
        scan_fused<<<1024, 256, 0, stream>>>(uu, dt2, pf2,
            Alog_f + (size_t)i * 8192, Alog_bk + (size_t)i * 8192,
            D_f + i * 512, D_bk + i * 512, y2);
        // outproj with gate fused in A-staging: h += ((yf+yb)*silu(z)) @ W^T
        gemm_mfma<64, 64, 4, 1, 1, 4, 0, true, false, 2, false><<<dim3(4, 64), 256, 0, stream>>>(
            y2, outproj_w + (size_t)i * 256 * 512, nullptr, h, M, 256, 512, 1024,
            xz, nullptr, nullptr, 0);
    }

    ln_kernel<float><<<M, 256, 0, stream>>>(h, nullptr, fng, fnb, hnf);
    gemm_nt<0, false, true><<<dim3(1, 64), 256, 0, stream>>>(
        hnf, fin_w, fin_b, htmp, M, 48, 256, 256);
    unpatch<<<768, 256, 0, stream>>>(htmp, out);
}

// Round 6
// 610.059 us; speedup vs baseline: 1.0764x; 1.0764x over previous
//
#include <hip/hip_runtime.h>
#include <hip/hip_bf16.h>

#define BB 16
#define LL 256
#define DD 256
#define DI 512
#define DS 16

typedef __attribute__((ext_vector_type(8))) short bf16x8;
typedef __attribute__((ext_vector_type(4))) short bf16x4;
typedef __attribute__((ext_vector_type(4))) float f32x4;

__device__ inline short f2bf(float f) {
    __hip_bfloat16 h = __float2bfloat16(f);
    return *reinterpret_cast<short*>(&h);
}
__device__ inline float bf2f_s(short s) {
    __hip_bfloat16 h = *reinterpret_cast<__hip_bfloat16*>(&s);
    return __bfloat162float(h);
}
__device__ inline void stf(float* p, float v) { *p = v; }
__device__ inline void stf(__hip_bfloat16* p, float v) { *p = __float2bfloat16(v); }

// ---------------- weight fp32->bf16 pre-convert (once per call) ----------------
// segments (elems): inproj 1048576 | xproj_f 131072 | xproj_bk 131072 |
//                   dtw_f 65536 | dtw_bk 65536 | outproj 524288   (total 1966080)
__global__ __launch_bounds__(256) void cvt_w(
    const float* __restrict__ s0, const float* __restrict__ s1,
    const float* __restrict__ s2, const float* __restrict__ s3,
    const float* __restrict__ s4, const float* __restrict__ s5,
    __hip_bfloat16* __restrict__ dst) {
    int i = blockIdx.x * 256 + threadIdx.x;      // vec4 index
    if (i >= 491520) return;
    int e = i * 4;
    const float* src; int off;
    if (e < 1048576)      { src = s0; off = e; }
    else if (e < 1179648) { src = s1; off = e - 1048576; }
    else if (e < 1310720) { src = s2; off = e - 1179648; }
    else if (e < 1376256) { src = s3; off = e - 1310720; }
    else if (e < 1441792) { src = s4; off = e - 1376256; }
    else                  { src = s5; off = e - 1441792; }
    float4 v = *(const float4*)(src + off);
    bf16x4 r;
    r[0] = f2bf(v.x); r[1] = f2bf(v.y); r[2] = f2bf(v.z); r[3] = f2bf(v.w);
    *(bf16x4*)((short*)dst + e) = r;
}

// ---------------- patch embed: h[b,l,d], 256 blocks ----------------
__global__ __launch_bounds__(256) void patch_embed(const float* __restrict__ x,
                                                   const float* __restrict__ pw,
                                                   const float* __restrict__ pb,
                                                   float* __restrict__ h) {
    int blk = blockIdx.x;           // b*16 + lg
    int b = blk >> 4, lg = blk & 15;
    int tid = threadIdx.x;
    __shared__ float pws[48 * 258];  // transposed, padded
    __shared__ float xs[16][48];
    for (int it = 0; it < 48; ++it) {
        int idx = tid + it * 256;    // 12288 total
        float v = pw[idx];
        int dd = idx / 48, k = idx - dd * 48;
        pws[k * 258 + dd] = v;
    }
    for (int idx = tid; idx < 16 * 48; idx += 256) {
        int li = idx / 48, k = idx - li * 48;
        int c = k >> 4, py = (k >> 2) & 3, px = k & 3;
        xs[li][k] = x[(size_t)(b * 3 + c) * 4096 + (lg * 4 + py) * 64 + li * 4 + px];
    }
    __syncthreads();
    float bv = pb[tid];
#pragma unroll 4
    for (int li = 0; li < 16; ++li) {
        float acc = bv;
#pragma unroll
        for (int k = 0; k < 48; ++k) acc += xs[li][k] * pws[k * 258 + tid];
        h[((size_t)(b * 256 + lg * 16 + li)) * 256 + tid] = acc;
    }
}

// ---------------- time embedding ----------------
__global__ void time_embed(const int* __restrict__ t, const float* __restrict__ tw1,
                           const float* __restrict__ tb1, const float* __restrict__ tw2,
                           const float* __restrict__ tb2, float* __restrict__ te) {
    int b = blockIdx.x, j = threadIdx.x;
    __shared__ float s0[256], s1[256];
    float tv = (float)t[b];
    if (j < 128) {
        float f = expf((float)j * (-9.210340371976184f / 127.f));
        float a = tv * f;
        s0[j] = sinf(a);
        s0[j + 128] = cosf(a);
    }
    __syncthreads();
    float acc = tb1[j];
    for (int k = 0; k < 256; ++k) acc += s0[k] * tw1[j * 256 + k];
    s1[j] = acc / (1.f + expf(-acc));
    __syncthreads();
    float acc2 = tb2[j];
    for (int k = 0; k < 256; ++k) acc2 += s1[k] * tw2[j * 256 + k];
    te[b * 256 + j] = acc2;
}

// ---------------- layernorm (optionally + te), templated output ----------------
template <typename TO>
__global__ void ln_kernel(const float* __restrict__ h, const float* __restrict__ te,
                          const float* __restrict__ g, const float* __restrict__ bta,
                          TO* __restrict__ out) {
    int row = blockIdx.x;         // b*L + l
    int b = row >> 8;
    int d = threadIdx.x;
    float v = h[(size_t)row * 256 + d] + (te ? te[b * 256 + d] : 0.f);
    float s = v, s2 = v * v;
#pragma unroll
    for (int o = 32; o; o >>= 1) {
        s += __shfl_down(s, o, 64);
        s2 += __shfl_down(s2, o, 64);
    }
    __shared__ float ws[4], ws2[4];
    int wid = threadIdx.x >> 6, lane = threadIdx.x & 63;
    if (lane == 0) { ws[wid] = s; ws2[wid] = s2; }
    __syncthreads();
    float mu = (ws[0] + ws[1] + ws[2] + ws[3]) * (1.f / 256.f);
    float m2 = (ws2[0] + ws2[1] + ws2[2] + ws2[3]) * (1.f / 256.f);
    float var = m2 - mu * mu;
    stf(&out[(size_t)row * 256 + d], (v - mu) * rsqrtf(var + 1e-5f) * g[d] + bta[d]);
}

// ---------------- bf16 MFMA GEMM (bf16 weights) ----------------
// C[M,N] (+)= act(A[M,K] @ W[N,K]^T + bias).  Generic BM; 4 waves (WM x WN).
// AMODE: 0 = A bf16 (lda stride), 1 = A fp32 (lda stride), 2 = gate-fuse:
//        A = y2 bf16 [M][1024], A2 = xz bf16 [M][1024]; a[row][j] = (yf+yb)*silu(z).
// OBF: write C as bf16 (else fp32; ADD only with fp32).
// Dual (nsplit>0): block-columns with n0>=nsplit use {A2,W2,bias2}.
template <int BM, int BN, int WM, int WN, int FM, int FN, int ACT, bool ADD,
          bool HASBIAS, int AMODE, bool OBF>
__global__ __launch_bounds__(256) void gemm_mfma(
    const void* __restrict__ Ap, const __hip_bfloat16* __restrict__ W,
    const float* __restrict__ bias, void* __restrict__ Cp,
    int M, int N, int K, int lda,
    const void* __restrict__ A2p, const __hip_bfloat16* __restrict__ W2,
    const float* __restrict__ bias2, int nsplit)
{
    constexpr int LDP = 40;   // padded bf16 elems per LDS row
    __shared__ __align__(16) short As[BM * LDP];
    __shared__ __align__(16) short Ws[BN * LDP];
    int tid = threadIdx.x;
    int lane = tid & 63;
    int w = tid >> 6;
    int wm, wn;
    if (WN == 1) { wm = w; wn = 0; } else { wm = w >> 1; wn = w & 1; }
    int m0 = blockIdx.y * BM;
    int n0 = blockIdx.x * BN;
    int wn0 = n0;
    if (nsplit > 0 && n0 >= nsplit) { Ap = A2p; W = W2; bias = bias2; wn0 = n0 - nsplit; }

    f32x4 acc[FM][FN];
#pragma unroll
    for (int i = 0; i < FM; ++i)
#pragma unroll
        for (int j = 0; j < FN; ++j) acc[i][j] = (f32x4){0.f, 0.f, 0.f, 0.f};

    for (int k0 = 0; k0 < K; k0 += 32) {
        // ---- stage A tile (BMx32 bf16) ----
        if (AMODE == 0) {
            for (int idx = tid; idx < BM * 4; idx += 256) {
                int row = idx >> 2, qc = idx & 3;
                const __hip_bfloat16* g = (const __hip_bfloat16*)Ap +
                    (size_t)(m0 + row) * lda + k0 + qc * 8;
                *(bf16x8*)&As[row * LDP + qc * 8] = *(const bf16x8*)g;
            }
        } else if (AMODE == 1) {
            for (int idx = tid; idx < BM * 4; idx += 256) {
                int row = idx >> 2, qc = idx & 3;
                const float* g = (const float*)Ap + (size_t)(m0 + row) * lda + k0 + qc * 8;
                float4 v0 = *(const float4*)g;
                float4 v1 = *(const float4*)(g + 4);
                union { bf16x8 v; short s[8]; } u8;
                u8.s[0] = f2bf(v0.x); u8.s[1] = f2bf(v0.y); u8.s[2] = f2bf(v0.z); u8.s[3] = f2bf(v0.w);
                u8.s[4] = f2bf(v1.x); u8.s[5] = f2bf(v1.y); u8.s[6] = f2bf(v1.z); u8.s[7] = f2bf(v1.w);
                *(bf16x8*)&As[row * LDP + qc * 8] = u8.v;
            }
        } else {
            for (int idx = tid; idx < BM * 4; idx += 256) {
                int row = idx >> 2, qc = idx & 3;
                size_t rb = (size_t)(m0 + row) * 1024 + k0 + qc * 8;
                union { bf16x8 v; short s[8]; } uf, ub, uz, r;
                uf.v = *(const bf16x8*)((const __hip_bfloat16*)Ap + rb);
                ub.v = *(const bf16x8*)((const __hip_bfloat16*)Ap + rb + 512);
                uz.v = *(const bf16x8*)((const __hip_bfloat16*)A2p + rb + 512);
#pragma unroll
                for (int e = 0; e < 8; ++e) {
                    float z = bf2f_s(uz.s[e]);
                    float sg = z / (1.f + __expf(-z));
                    r.s[e] = f2bf((bf2f_s(uf.s[e]) + bf2f_s(ub.s[e])) * sg);
                }
                *(bf16x8*)&As[row * LDP + qc * 8] = r.v;
            }
        }
        // ---- stage W tile (BNx32, bf16 direct) ----
        for (int idx = tid; idx < BN * 4; idx += 256) {
            int row = idx >> 2, qc = idx & 3;
            const __hip_bfloat16* g = W + (size_t)(wn0 + row) * K + k0 + qc * 8;
            *(bf16x8*)&Ws[row * LDP + qc * 8] = *(const bf16x8*)g;
        }
        __syncthreads();
        int kg = lane >> 4, r = lane & 15;
        bf16x8 af[FM], bfr[FN];
#pragma unroll
        for (int i = 0; i < FM; ++i)
            af[i] = *(const bf16x8*)&As[(wm * FM * 16 + i * 16 + r) * LDP + kg * 8];
#pragma unroll
        for (int j = 0; j < FN; ++j)
            bfr[j] = *(const bf16x8*)&Ws[(wn * FN * 16 + j * 16 + r) * LDP + kg * 8];
#pragma unroll
        for (int i = 0; i < FM; ++i)
#pragma unroll
            for (int j = 0; j < FN; ++j)
                acc[i][j] = __builtin_amdgcn_mfma_f32_16x16x32_bf16(af[i], bfr[j], acc[i][j], 0, 0, 0);
        __syncthreads();
    }
    // epilogue: C row=(lane>>4)*4+reg, col=lane&15
    int r = lane & 15, qg = lane >> 4;
#pragma unroll
    for (int i = 0; i < FM; ++i) {
#pragma unroll
        for (int j = 0; j < FN; ++j) {
            int col = n0 + wn * FN * 16 + j * 16 + r;
            int colw = wn0 + wn * FN * 16 + j * 16 + r;
            float bv = HASBIAS ? bias[colw] : 0.f;
#pragma unroll
            for (int q = 0; q < 4; ++q) {
                int rowm = m0 + wm * FM * 16 + i * 16 + qg * 4 + q;
                float v = acc[i][j][q] + bv;
                if (ACT == 1) v = (v > 20.f) ? v : log1pf(__expf(v));
                size_t o = (size_t)rowm * N + col;
                if (OBF) ((__hip_bfloat16*)Cp)[o] = __float2bfloat16(v);
                else if (ADD) ((float*)Cp)[o] += v;
                else ((float*)Cp)[o] = v;
            }
        }
    }
}

// ---------------- fp32 GEMM for the small head ----------------
template <int ACT, bool ADD, bool HASBIAS>
__global__ __launch_bounds__(256) void gemm_nt(const float* __restrict__ A,
                                               const float* __restrict__ W,
                                               const float* __restrict__ bias,
                                               float* __restrict__ C,
                                               int M, int N, int K, int lda) {
    __shared__ float Asm[16][65];
    __shared__ float Wsm[16][65];
    int tx = threadIdx.x & 15, ty = threadIdx.x >> 4;
    int m0 = blockIdx.y * 64, n0 = blockIdx.x * 64;
    float acc[4][4] = {};
    for (int k0 = 0; k0 < K; k0 += 16) {
#pragma unroll
        for (int i = 0; i < 4; ++i) {
            int idx = threadIdx.x + i * 256;
            int rr = idx >> 4, cc = idx & 15;
            Asm[cc][rr] = A[(size_t)(m0 + rr) * lda + k0 + cc];
            int n = n0 + rr;
            Wsm[cc][rr] = (n < N) ? W[(size_t)n * K + k0 + cc] : 0.f;
        }
        __syncthreads();
#pragma unroll
        for (int k = 0; k < 16; ++k) {
            float av[4], wv[4];
#pragma unroll
            for (int i = 0; i < 4; ++i) av[i] = Asm[k][ty * 4 + i];
#pragma unroll
            for (int j = 0; j < 4; ++j) wv[j] = Wsm[k][tx * 4 + j];
#pragma unroll
            for (int i = 0; i < 4; ++i)
#pragma unroll
                for (int j = 0; j < 4; ++j) acc[i][j] += av[i] * wv[j];
        }
        __syncthreads();
    }
#pragma unroll
    for (int i = 0; i < 4; ++i) {
        int m = m0 + ty * 4 + i;
#pragma unroll
        for (int j = 0; j < 4; ++j) {
            int n = n0 + tx * 4 + j;
            if (n < N) {
                float v = acc[i][j];
                if (HASBIAS) v += bias[n];
                if (ADD) C[(size_t)m * N + n] += v;
                else C[(size_t)m * N + n] = v;
            }
        }
    }
}

// ---------------- causal depthwise conv (k=4) + silu, vectorized bf16x8 ----------------
__global__ __launch_bounds__(256) void conv_silu(
    const __hip_bfloat16* __restrict__ xz, const float* __restrict__ cw,
    const float* __restrict__ cb, __hip_bfloat16* __restrict__ u) {
    int g = blockIdx.x * 4 + (threadIdx.x >> 6);   // row index b*L + l
    int lane = threadIdx.x & 63;
    int l = g & 255;
    int d0 = lane * 8;
    const __hip_bfloat16* base = xz + (size_t)g * 1024 + d0;
    union { bf16x8 v; short s[8]; } t0, t1, t2, t3, r;
    bf16x8 zz = {};
    t3.v = *(const bf16x8*)base;
    t2.v = (l >= 1) ? *(const bf16x8*)(base - 1024) : zz;
    t1.v = (l >= 2) ? *(const bf16x8*)(base - 2048) : zz;
    t0.v = (l >= 3) ? *(const bf16x8*)(base - 3072) : zz;
#pragma unroll
    for (int e = 0; e < 8; ++e) {
        int d = d0 + e;
        const float4 wv = *(const float4*)(cw + d * 4);
        float acc = cb[d] + bf2f_s(t0.s[e]) * wv.x + bf2f_s(t1.s[e]) * wv.y +
                    bf2f_s(t2.s[e]) * wv.z + bf2f_s(t3.s[e]) * wv.w;
        r.s[e] = f2bf(acc / (1.f + __expf(-acc)));
    }
    *(bf16x8*)(u + (size_t)g * 512 + d0) = r.v;
}

// ================= fused chunked SSM scan v4 =================
// grid = 512: blk = ((b*2+dir)*16 + dg), dg selects 32 channels (coalesced 64B/wave).
// 512 threads = 16 chunks (cc=tid>>5) x 32 channels (dl=tid&31); chunk len 16.
// LDS exactly 80 KB -> 2 blocks/CU (16 waves).
__global__ __launch_bounds__(512) void scan_fused(
    const __hip_bfloat16* __restrict__ u, const __hip_bfloat16* __restrict__ dt2,
    const float* __restrict__ pf2,
    const float* __restrict__ Alog_f, const float* __restrict__ Alog_b,
    const float* __restrict__ Dv_f, const float* __restrict__ Dv_b,
    __hip_bfloat16* __restrict__ y2)
{
    int blk = blockIdx.x;
    int dg = blk & 15;
    int bd = blk >> 4;
    int dir = bd & 1, b = bd >> 1;
    int tid = threadIdx.x;
    int dl = tid & 31, cc = tid >> 5;
    int d = dg * 32 + dl;
    int poff = dir ? 64 : 0;
    int doff = dir ? 512 : 0;
    const float* Alog = dir ? Alog_b : Alog_f;
    float Dval = (dir ? Dv_b : Dv_f)[d];

    __shared__ short Bs[256][16];      // bf16, broadcast reads (2-way max: free)
    __shared__ short Cs[256][16];
    __shared__ float Ps[16][16][32];   // [s][chunk][ch]
    __shared__ float Fs[16][16][32];

    for (int idx = tid; idx < 4096; idx += 512) {
        int i = idx >> 4, s = idx & 15;
        int tt = dir ? 255 - i : i;
        const float* pr = pf2 + ((size_t)b * 256 + tt) * 128 + poff;
        Bs[i][s] = f2bf(pr[32 + s]);
        Cs[i][s] = f2bf(pr[48 + s]);
    }
    float A2[16];                    // -exp(Alog) * log2(e)  (for exp2f)
    {
        const float* ap = Alog + d * 16;
#pragma unroll
        for (int s = 0; s < 16; ++s) A2[s] = -__expf(ap[s]) * 1.44269504f;
    }
    __syncthreads();

    int i0 = cc * 16;
    int row0 = b * 256 + (dir ? 255 - i0 : i0);
    int stp = dir ? -1 : 1;
    const __hip_bfloat16* dtp = dt2 + (size_t)row0 * 1024 + doff + d;
    const __hip_bfloat16* up  = u  + (size_t)row0 * 512 + d;

    float h[16];
#pragma unroll
    for (int s = 0; s < 16; ++s) h[s] = 0.f;
    float S = 0.f;
#pragma unroll 4
    for (int k = 0; k < 16; ++k) {
        float dtv = __bfloat162float(dtp[(k * stp) * 1024]);
        float uv  = __bfloat162float(up[(k * stp) * 512]);
        S += dtv;
        float du = dtv * uv;
        int i = i0 + k;
#pragma unroll
        for (int s = 0; s < 16; ++s)
            h[s] = exp2f(dtv * A2[s]) * h[s] + du * bf2f_s(Bs[i][s]);
    }
#pragma unroll
    for (int s = 0; s < 16; ++s) {
        Ps[s][cc][dl] = exp2f(A2[s] * S);
        Fs[s][cc][dl] = h[s];
    }
    __syncthreads();
    {   // prefix over 16 chunks: 512 (s,ch) pairs, exactly 1 per thread
        int s2 = tid >> 5, dl2 = tid & 31;
        float hh = 0.f;
#pragma unroll
        for (int c2 = 0; c2 < 16; ++c2) {
            float pv = Ps[s2][c2][dl2];
            float fv = Fs[s2][c2][dl2];
            Ps[s2][c2][dl2] = hh;       // Hin for chunk c2
            hh = fv + pv * hh;
        }
    }
    __syncthreads();
#pragma unroll
    for (int s = 0; s < 16; ++s) h[s] = Ps[s][cc][dl];
    __hip_bfloat16* yp = y2 + (size_t)row0 * 1024 + doff + d;
#pragma unroll 4
    for (int k = 0; k < 16; ++k) {
        float dtv = __bfloat162float(dtp[(k * stp) * 1024]);
        float uv  = __bfloat162float(up[(k * stp) * 512]);
        float du = dtv * uv;
        float acc = 0.f;
        int i = i0 + k;
#pragma unroll
        for (int s = 0; s < 16; ++s) {
            h[s] = exp2f(dtv * A2[s]) * h[s] + du * bf2f_s(Bs[i][s]);
            acc += h[s] * bf2f_s(Cs[i][s]);
        }
        yp[(k * stp) * 1024] = __float2bfloat16(acc + uv * Dval);
    }
}

// ---------------- unpatchify ----------------
__global__ void unpatch(const float* __restrict__ tmp, float* __restrict__ out) {
    int i = blockIdx.x * blockDim.x + threadIdx.x;
    if (i >= 16 * 3 * 64 * 64) return;
    int b = i / (3 * 4096);
    int rem = i % (3 * 4096);
    int c = rem / 4096;
    int pos = rem % 4096;
    int hy = pos >> 6, wx = pos & 63;
    int l = (hy >> 2) * 16 + (wx >> 2);
    int jj = c * 16 + (hy & 3) * 4 + (wx & 3);
    out[i] = tmp[((size_t)b * 256 + l) * 48 + jj];
}

extern "C" void kernel_launch(void* const* d_in, const int* in_sizes, int n_in,
                              void* d_out, int out_size, void* d_ws, size_t ws_size,
                              hipStream_t stream) {
    const float* x        = (const float*)d_in[0];
    const int*   t        = (const int*)d_in[1];
    const float* patch_w  = (const float*)d_in[2];
    const float* patch_b  = (const float*)d_in[3];
    const float* tw1      = (const float*)d_in[4];
    const float* tb1      = (const float*)d_in[5];
    const float* tw2      = (const float*)d_in[6];
    const float* tb2      = (const float*)d_in[7];
    const float* norm_g   = (const float*)d_in[8];
    const float* norm_b   = (const float*)d_in[9];
    const float* inproj_w = (const float*)d_in[10];
    const float* conv_w   = (const float*)d_in[11];
    const float* conv_b   = (const float*)d_in[12];
    const float* Alog_f   = (const float*)d_in[13];
    const float* D_f      = (const float*)d_in[14];
    const float* xproj_f  = (const float*)d_in[15];
    const float* dtw_f    = (const float*)d_in[16];
    const float* dtb_f    = (const float*)d_in[17];
    const float* Alog_bk  = (const float*)d_in[18];
    const float* D_bk     = (const float*)d_in[19];
    const float* xproj_bk = (const float*)d_in[20];
    const float* dtw_bk   = (const float*)d_in[21];
    const float* dtb_bk   = (const float*)d_in[22];
    const float* outproj_w= (const float*)d_in[23];
    const float* fng      = (const float*)d_in[24];
    const float* fnb      = (const float*)d_in[25];
    const float* fin_w    = (const float*)d_in[26];
    const float* fin_b    = (const float*)d_in[27];
    float* out = (float*)d_out;

    char* base = (char*)d_ws;
    float*          te  = (float*)base;                                   // 16 KB
    float*          h   = (float*)(base + (16UL << 10));                  // 4 MB
    __hip_bfloat16* hn  = (__hip_bfloat16*)(base + (16UL << 10) + (4UL << 20));   // 2 MB
    __hip_bfloat16* xz  = (__hip_bfloat16*)((char*)hn + (2UL << 20));     // 8 MB
    __hip_bfloat16* uu  = (__hip_bfloat16*)((char*)xz + (8UL << 20));     // 4 MB
    float*          pf2 = (float*)((char*)uu + (4UL << 20));              // 2 MB
    __hip_bfloat16* dt2 = (__hip_bfloat16*)((char*)pf2 + (2UL << 20));    // 8 MB
    __hip_bfloat16* y2  = (__hip_bfloat16*)((char*)dt2 + (8UL << 20));    // 8 MB
    __hip_bfloat16* wbf = (__hip_bfloat16*)((char*)y2 + (8UL << 20));     // 4 MB
    float*          hnf = (float*)dt2;   // reuse after last scan
    float*          htmp= pf2;           // head tmp reuse

    // bf16 weight segment offsets (elems)
    __hip_bfloat16* w_in  = wbf;               // 4 x 1024*256
    __hip_bfloat16* w_xf  = wbf + 1048576;     // 4 x 64*512
    __hip_bfloat16* w_xb  = wbf + 1179648;     // 4 x 64*512
    __hip_bfloat16* w_dtf = wbf + 1310720;     // 4 x 512*32
    __hip_bfloat16* w_dtb = wbf + 1376256;     // 4 x 512*32
    __hip_bfloat16* w_out = wbf + 1441792;     // 4 x 256*512

    const int M = BB * LL;                // 4096

    cvt_w<<<1920, 256, 0, stream>>>(inproj_w, xproj_f, xproj_bk, dtw_f, dtw_bk,
                                    outproj_w, wbf);
    patch_embed<<<256, 256, 0, stream>>>(x, patch_w, patch_b, h);
    time_embed<<<BB, 256, 0, stream>>>(t, tw1, tb1, tw2, tb2, te);

    for (int i = 0; i < 4; ++i) {
        ln_kernel<__hip_bfloat16><<<M, 256, 0, stream>>>(
            h, te, norm_g + i * 256, norm_b + i * 256, hn);
        // inproj: xz[4096,1024] = hn @ W^T   (bf16 out)
        gemm_mfma<128, 128, 2, 2, 4, 4, 0, false, false, 0, true><<<dim3(8, 32), 256, 0, stream>>>(
            hn, w_in + (size_t)i * 262144, nullptr, xz, M, 1024, 256, 256,
            nullptr, nullptr, nullptr, 0);
        conv_silu<<<1024, 256, 0, stream>>>(xz, conv_w + i * 2048, conv_b + i * 512, uu);
        // fused xproj f|b: pf2[4096,128]  (fp32 out)
        gemm_mfma<32, 64, 2, 2, 1, 2, 0, false, false, 0, false><<<dim3(2, 128), 256, 0, stream>>>(
            uu, w_xf + (size_t)i * 32768, nullptr, pf2, M, 128, 512, 512,
            uu, w_xb + (size_t)i * 32768, nullptr, 64);
        // fused dt f|b: dt2[4096,1024] = softplus(pf2[:, dtp] @ dtw^T + dtb)  (bf16 out)
        gemm_mfma<128, 128, 2, 2, 4, 4, 1, false, true, 1, true><<<dim3(8, 32), 256, 0, stream>>>(
            pf2, w_dtf + (size_t)i * 16384, dtb_f + i * 512, dt2, M, 1024, 32, 128,
            pf2 + 64, w_dtb + (size_t)i * 16384, dtb_bk + i * 512, 512);
        scan_fused<<<512, 512, 0, stream>>>(uu, dt2, pf2,
            Alog_f + (size_t)i * 8192, Alog_bk + (size_t)i * 8192,
            D_f + i * 512, D_bk + i * 512, y2);
        // outproj with gate fused in A-staging: h += ((yf+yb)*silu(z)) @ W^T
        gemm_mfma<64, 64, 4, 1, 1, 4, 0, true, false, 2, false><<<dim3(4, 64), 256, 0, stream>>>(
            y2, w_out + (size_t)i * 131072, nullptr, h, M, 256, 512, 1024,
            xz, nullptr, nullptr, 0);
    }

    ln_kernel<float><<<M, 256, 0, stream>>>(h, nullptr, fng, fnb, hnf);
    gemm_nt<0, false, true><<<dim3(1, 64), 256, 0, stream>>>(
        hnf, fin_w, fin_b, htmp, M, 48, 256, 256);
    unpatch<<<768, 256, 0, stream>>>(htmp, out);
}

// Round 7
// 561.300 us; speedup vs baseline: 1.1699x; 1.0869x over previous
//
#include <hip/hip_runtime.h>
#include <hip/hip_bf16.h>

#define BB 16
#define LL 256
#define DD 256
#define DI 512
#define DS 16

typedef __attribute__((ext_vector_type(8))) short bf16x8;
typedef __attribute__((ext_vector_type(4))) short bf16x4;
typedef __attribute__((ext_vector_type(4))) float f32x4;

__device__ inline short f2bf(float f) {
    __hip_bfloat16 h = __float2bfloat16(f);
    return *reinterpret_cast<short*>(&h);
}
__device__ inline float bf2f_s(short s) {
    __hip_bfloat16 h = *reinterpret_cast<__hip_bfloat16*>(&s);
    return __bfloat162float(h);
}
__device__ inline void stf(float* p, float v) { *p = v; }
__device__ inline void stf(__hip_bfloat16* p, float v) { *p = __float2bfloat16(v); }

// unpack 16 contiguous bf16 (32B, 16B-aligned) from LDS into 16 floats
__device__ inline void unpack16(const short* p, float* f) {
    bf16x8 v0 = *(const bf16x8*)p;
    bf16x8 v1 = *(const bf16x8*)(p + 8);
    const unsigned* a = (const unsigned*)&v0;
    const unsigned* b = (const unsigned*)&v1;
#pragma unroll
    for (int j = 0; j < 4; ++j) {
        f[2 * j]     = __uint_as_float(a[j] << 16);
        f[2 * j + 1] = __uint_as_float(a[j] & 0xFFFF0000u);
        f[8 + 2 * j]     = __uint_as_float(b[j] << 16);
        f[8 + 2 * j + 1] = __uint_as_float(b[j] & 0xFFFF0000u);
    }
}

// ---------------- weight fp32->bf16 pre-convert (once per call) ----------------
__global__ __launch_bounds__(256) void cvt_w(
    const float* __restrict__ s0, const float* __restrict__ s1,
    const float* __restrict__ s2, const float* __restrict__ s3,
    const float* __restrict__ s4, const float* __restrict__ s5,
    __hip_bfloat16* __restrict__ dst) {
    int i = blockIdx.x * 256 + threadIdx.x;      // vec4 index
    if (i >= 491520) return;
    int e = i * 4;
    const float* src; int off;
    if (e < 1048576)      { src = s0; off = e; }
    else if (e < 1179648) { src = s1; off = e - 1048576; }
    else if (e < 1310720) { src = s2; off = e - 1179648; }
    else if (e < 1376256) { src = s3; off = e - 1310720; }
    else if (e < 1441792) { src = s4; off = e - 1376256; }
    else                  { src = s5; off = e - 1441792; }
    float4 v = *(const float4*)(src + off);
    bf16x4 r;
    r[0] = f2bf(v.x); r[1] = f2bf(v.y); r[2] = f2bf(v.z); r[3] = f2bf(v.w);
    *(bf16x4*)((short*)dst + e) = r;
}

// ---------------- patch embed ----------------
__global__ __launch_bounds__(256) void patch_embed(const float* __restrict__ x,
                                                   const float* __restrict__ pw,
                                                   const float* __restrict__ pb,
                                                   float* __restrict__ h) {
    int blk = blockIdx.x;           // b*16 + lg
    int b = blk >> 4, lg = blk & 15;
    int tid = threadIdx.x;
    __shared__ float pws[48 * 258];
    __shared__ float xs[16][48];
    for (int it = 0; it < 48; ++it) {
        int idx = tid + it * 256;
        float v = pw[idx];
        int dd = idx / 48, k = idx - dd * 48;
        pws[k * 258 + dd] = v;
    }
    for (int idx = tid; idx < 16 * 48; idx += 256) {
        int li = idx / 48, k = idx - li * 48;
        int c = k >> 4, py = (k >> 2) & 3, px = k & 3;
        xs[li][k] = x[(size_t)(b * 3 + c) * 4096 + (lg * 4 + py) * 64 + li * 4 + px];
    }
    __syncthreads();
    float bv = pb[tid];
#pragma unroll 4
    for (int li = 0; li < 16; ++li) {
        float acc = bv;
#pragma unroll
        for (int k = 0; k < 48; ++k) acc += xs[li][k] * pws[k * 258 + tid];
        h[((size_t)(b * 256 + lg * 16 + li)) * 256 + tid] = acc;
    }
}

// ---------------- time embedding ----------------
__global__ void time_embed(const int* __restrict__ t, const float* __restrict__ tw1,
                           const float* __restrict__ tb1, const float* __restrict__ tw2,
                           const float* __restrict__ tb2, float* __restrict__ te) {
    int b = blockIdx.x, j = threadIdx.x;
    __shared__ float s0[256], s1[256];
    float tv = (float)t[b];
    if (j < 128) {
        float f = expf((float)j * (-9.210340371976184f / 127.f));
        float a = tv * f;
        s0[j] = sinf(a);
        s0[j + 128] = cosf(a);
    }
    __syncthreads();
    float acc = tb1[j];
    for (int k = 0; k < 256; ++k) acc += s0[k] * tw1[j * 256 + k];
    s1[j] = acc / (1.f + expf(-acc));
    __syncthreads();
    float acc2 = tb2[j];
    for (int k = 0; k < 256; ++k) acc2 += s1[k] * tw2[j * 256 + k];
    te[b * 256 + j] = acc2;
}

// ---------------- layernorm ----------------
template <typename TO>
__global__ void ln_kernel(const float* __restrict__ h, const float* __restrict__ te,
                          const float* __restrict__ g, const float* __restrict__ bta,
                          TO* __restrict__ out) {
    int row = blockIdx.x;
    int b = row >> 8;
    int d = threadIdx.x;
    float v = h[(size_t)row * 256 + d] + (te ? te[b * 256 + d] : 0.f);
    float s = v, s2 = v * v;
#pragma unroll
    for (int o = 32; o; o >>= 1) {
        s += __shfl_down(s, o, 64);
        s2 += __shfl_down(s2, o, 64);
    }
    __shared__ float ws[4], ws2[4];
    int wid = threadIdx.x >> 6, lane = threadIdx.x & 63;
    if (lane == 0) { ws[wid] = s; ws2[wid] = s2; }
    __syncthreads();
    float mu = (ws[0] + ws[1] + ws[2] + ws[3]) * (1.f / 256.f);
    float m2 = (ws2[0] + ws2[1] + ws2[2] + ws2[3]) * (1.f / 256.f);
    float var = m2 - mu * mu;
    stf(&out[(size_t)row * 256 + d], (v - mu) * rsqrtf(var + 1e-5f) * g[d] + bta[d]);
}

// ---------------- bf16 MFMA GEMM (bf16 weights) ----------------
template <int BM, int BN, int WM, int WN, int FM, int FN, int ACT, bool ADD,
          bool HASBIAS, int AMODE, bool OBF>
__global__ __launch_bounds__(256) void gemm_mfma(
    const void* __restrict__ Ap, const __hip_bfloat16* __restrict__ W,
    const float* __restrict__ bias, void* __restrict__ Cp,
    int M, int N, int K, int lda,
    const void* __restrict__ A2p, const __hip_bfloat16* __restrict__ W2,
    const float* __restrict__ bias2, int nsplit)
{
    constexpr int LDP = 40;
    __shared__ __align__(16) short As[BM * LDP];
    __shared__ __align__(16) short Ws[BN * LDP];
    int tid = threadIdx.x;
    int lane = tid & 63;
    int w = tid >> 6;
    int wm, wn;
    if (WN == 1) { wm = w; wn = 0; } else { wm = w >> 1; wn = w & 1; }
    int m0 = blockIdx.y * BM;
    int n0 = blockIdx.x * BN;
    int wn0 = n0;
    if (nsplit > 0 && n0 >= nsplit) { Ap = A2p; W = W2; bias = bias2; wn0 = n0 - nsplit; }

    f32x4 acc[FM][FN];
#pragma unroll
    for (int i = 0; i < FM; ++i)
#pragma unroll
        for (int j = 0; j < FN; ++j) acc[i][j] = (f32x4){0.f, 0.f, 0.f, 0.f};

    for (int k0 = 0; k0 < K; k0 += 32) {
        if (AMODE == 0) {
            for (int idx = tid; idx < BM * 4; idx += 256) {
                int row = idx >> 2, qc = idx & 3;
                const __hip_bfloat16* g = (const __hip_bfloat16*)Ap +
                    (size_t)(m0 + row) * lda + k0 + qc * 8;
                *(bf16x8*)&As[row * LDP + qc * 8] = *(const bf16x8*)g;
            }
        } else if (AMODE == 1) {
            for (int idx = tid; idx < BM * 4; idx += 256) {
                int row = idx >> 2, qc = idx & 3;
                const float* g = (const float*)Ap + (size_t)(m0 + row) * lda + k0 + qc * 8;
                float4 v0 = *(const float4*)g;
                float4 v1 = *(const float4*)(g + 4);
                union { bf16x8 v; short s[8]; } u8;
                u8.s[0] = f2bf(v0.x); u8.s[1] = f2bf(v0.y); u8.s[2] = f2bf(v0.z); u8.s[3] = f2bf(v0.w);
                u8.s[4] = f2bf(v1.x); u8.s[5] = f2bf(v1.y); u8.s[6] = f2bf(v1.z); u8.s[7] = f2bf(v1.w);
                *(bf16x8*)&As[row * LDP + qc * 8] = u8.v;
            }
        } else {
            for (int idx = tid; idx < BM * 4; idx += 256) {
                int row = idx >> 2, qc = idx & 3;
                size_t rb = (size_t)(m0 + row) * 1024 + k0 + qc * 8;
                union { bf16x8 v; short s[8]; } uf, ub, uz, r;
                uf.v = *(const bf16x8*)((const __hip_bfloat16*)Ap + rb);
                ub.v = *(const bf16x8*)((const __hip_bfloat16*)Ap + rb + 512);
                uz.v = *(const bf16x8*)((const __hip_bfloat16*)A2p + rb + 512);
#pragma unroll
                for (int e = 0; e < 8; ++e) {
                    float z = bf2f_s(uz.s[e]);
                    float sg = z / (1.f + __expf(-z));
                    r.s[e] = f2bf((bf2f_s(uf.s[e]) + bf2f_s(ub.s[e])) * sg);
                }
                *(bf16x8*)&As[row * LDP + qc * 8] = r.v;
            }
        }
        for (int idx = tid; idx < BN * 4; idx += 256) {
            int row = idx >> 2, qc = idx & 3;
            const __hip_bfloat16* g = W + (size_t)(wn0 + row) * K + k0 + qc * 8;
            *(bf16x8*)&Ws[row * LDP + qc * 8] = *(const bf16x8*)g;
        }
        __syncthreads();
        int kg = lane >> 4, r = lane & 15;
        bf16x8 af[FM], bfr[FN];
#pragma unroll
        for (int i = 0; i < FM; ++i)
            af[i] = *(const bf16x8*)&As[(wm * FM * 16 + i * 16 + r) * LDP + kg * 8];
#pragma unroll
        for (int j = 0; j < FN; ++j)
            bfr[j] = *(const bf16x8*)&Ws[(wn * FN * 16 + j * 16 + r) * LDP + kg * 8];
#pragma unroll
        for (int i = 0; i < FM; ++i)
#pragma unroll
            for (int j = 0; j < FN; ++j)
                acc[i][j] = __builtin_amdgcn_mfma_f32_16x16x32_bf16(af[i], bfr[j], acc[i][j], 0, 0, 0);
        __syncthreads();
    }
    int r = lane & 15, qg = lane >> 4;
#pragma unroll
    for (int i = 0; i < FM; ++i) {
#pragma unroll
        for (int j = 0; j < FN; ++j) {
            int col = n0 + wn * FN * 16 + j * 16 + r;
            int colw = wn0 + wn * FN * 16 + j * 16 + r;
            float bv = HASBIAS ? bias[colw] : 0.f;
#pragma unroll
            for (int q = 0; q < 4; ++q) {
                int rowm = m0 + wm * FM * 16 + i * 16 + qg * 4 + q;
                float v = acc[i][j][q] + bv;
                if (ACT == 1) v = (v > 20.f) ? v : log1pf(__expf(v));
                size_t o = (size_t)rowm * N + col;
                if (OBF) ((__hip_bfloat16*)Cp)[o] = __float2bfloat16(v);
                else if (ADD) ((float*)Cp)[o] += v;
                else ((float*)Cp)[o] = v;
            }
        }
    }
}

// ---------------- fp32 GEMM for the small head ----------------
template <int ACT, bool ADD, bool HASBIAS>
__global__ __launch_bounds__(256) void gemm_nt(const float* __restrict__ A,
                                               const float* __restrict__ W,
                                               const float* __restrict__ bias,
                                               float* __restrict__ C,
                                               int M, int N, int K, int lda) {
    __shared__ float Asm[16][65];
    __shared__ float Wsm[16][65];
    int tx = threadIdx.x & 15, ty = threadIdx.x >> 4;
    int m0 = blockIdx.y * 64, n0 = blockIdx.x * 64;
    float acc[4][4] = {};
    for (int k0 = 0; k0 < K; k0 += 16) {
#pragma unroll
        for (int i = 0; i < 4; ++i) {
            int idx = threadIdx.x + i * 256;
            int rr = idx >> 4, cc = idx & 15;
            Asm[cc][rr] = A[(size_t)(m0 + rr) * lda + k0 + cc];
            int n = n0 + rr;
            Wsm[cc][rr] = (n < N) ? W[(size_t)n * K + k0 + cc] : 0.f;
        }
        __syncthreads();
#pragma unroll
        for (int k = 0; k < 16; ++k) {
            float av[4], wv[4];
#pragma unroll
            for (int i = 0; i < 4; ++i) av[i] = Asm[k][ty * 4 + i];
#pragma unroll
            for (int j = 0; j < 4; ++j) wv[j] = Wsm[k][tx * 4 + j];
#pragma unroll
            for (int i = 0; i < 4; ++i)
#pragma unroll
                for (int j = 0; j < 4; ++j) acc[i][j] += av[i] * wv[j];
        }
        __syncthreads();
    }
#pragma unroll
    for (int i = 0; i < 4; ++i) {
        int m = m0 + ty * 4 + i;
#pragma unroll
        for (int j = 0; j < 4; ++j) {
            int n = n0 + tx * 4 + j;
            if (n < N) {
                float v = acc[i][j];
                if (HASBIAS) v += bias[n];
                if (ADD) C[(size_t)m * N + n] += v;
                else C[(size_t)m * N + n] = v;
            }
        }
    }
}

// ---------------- causal depthwise conv (k=4) + silu ----------------
__global__ __launch_bounds__(256) void conv_silu(
    const __hip_bfloat16* __restrict__ xz, const float* __restrict__ cw,
    const float* __restrict__ cb, __hip_bfloat16* __restrict__ u) {
    int g = blockIdx.x * 4 + (threadIdx.x >> 6);
    int lane = threadIdx.x & 63;
    int l = g & 255;
    int d0 = lane * 8;
    const __hip_bfloat16* base = xz + (size_t)g * 1024 + d0;
    union { bf16x8 v; short s[8]; } t0, t1, t2, t3, r;
    bf16x8 zz = {};
    t3.v = *(const bf16x8*)base;
    t2.v = (l >= 1) ? *(const bf16x8*)(base - 1024) : zz;
    t1.v = (l >= 2) ? *(const bf16x8*)(base - 2048) : zz;
    t0.v = (l >= 3) ? *(const bf16x8*)(base - 3072) : zz;
#pragma unroll
    for (int e = 0; e < 8; ++e) {
        int d = d0 + e;
        const float4 wv = *(const float4*)(cw + d * 4);
        float acc = cb[d] + bf2f_s(t0.s[e]) * wv.x + bf2f_s(t1.s[e]) * wv.y +
                    bf2f_s(t2.s[e]) * wv.z + bf2f_s(t3.s[e]) * wv.w;
        r.s[e] = f2bf(acc / (1.f + __expf(-acc)));
    }
    *(bf16x8*)(u + (size_t)g * 512 + d0) = r.v;
}

// ================= fused chunked SSM scan v5 =================
// grid = 512: blk = ((b*2+dir)*16 + dg); 512 threads = 16 chunks x 32 channels.
// Pass A: local scan, y_local written.  Prefix in LDS (P|F bf16-packed, Hin f32
// in place).  Pass B: y += Horner correction using Hin.  Decay via powers of one
// exp2 when A[s] = (s+1)*A[0] (runtime-checked, wave-uniform; generic fallback).
__global__ __launch_bounds__(512) void scan_fused(
    const __hip_bfloat16* __restrict__ u, const __hip_bfloat16* __restrict__ dt2,
    const float* __restrict__ pf2,
    const float* __restrict__ Alog_f, const float* __restrict__ Alog_b,
    const float* __restrict__ Dv_f, const float* __restrict__ Dv_b,
    __hip_bfloat16* __restrict__ y2)
{
    int blk = blockIdx.x;
    int dg = blk & 15;
    int bd = blk >> 4;
    int dir = bd & 1, b = bd >> 1;
    int tid = threadIdx.x;
    int dl = tid & 31, cc = tid >> 5;
    int d = dg * 32 + dl;
    int poff = dir ? 64 : 0;
    int doff = dir ? 512 : 0;
    const float* Alog = dir ? Alog_b : Alog_f;
    float Dval = (dir ? Dv_b : Dv_f)[d];

    __shared__ __align__(16) short Bs[256 * 16];   // 8 KB
    __shared__ __align__(16) short Cs[256 * 16];   // 8 KB
    __shared__ unsigned PF[16 * 16 * 32];          // 32 KB: P(lo)|F(hi) packed; Hin f32 in place

    for (int idx = tid; idx < 4096; idx += 512) {
        int i = idx >> 4, s = idx & 15;
        int tt = dir ? 255 - i : i;
        const float* pr = pf2 + ((size_t)b * 256 + tt) * 128 + poff;
        Bs[i * 16 + s] = f2bf(pr[32 + s]);
        Cs[i * 16 + s] = f2bf(pr[48 + s]);
    }
    float A2[16];
    bool fast;
    {
        const float* ap = Alog + d * 16;
        float A0 = -__expf(ap[0]);
        fast = true;
#pragma unroll
        for (int s = 0; s < 16; ++s) {
            float As_ = -__expf(ap[s]);
            A2[s] = As_ * 1.44269504f;
            fast = fast && (fabsf(As_ - (float)(s + 1) * A0) <= 1e-3f * (float)(s + 1));
        }
    }
    float A0c = A2[0];
    __syncthreads();

    int i0 = cc * 16;
    int row0 = b * 256 + (dir ? 255 - i0 : i0);
    int stpE = dir ? -1 : 1;
    int dstep = stpE * 1024, ustep = stpE * 512;
    const __hip_bfloat16* dtp0 = dt2 + (size_t)row0 * 1024 + doff + d;
    const __hip_bfloat16* up0  = u  + (size_t)row0 * 512 + d;
    __hip_bfloat16* yp0 = y2 + (size_t)row0 * 1024 + doff + d;

    // ---- Pass A: local scan, write y_local ----
    float h[16];
#pragma unroll
    for (int s = 0; s < 16; ++s) h[s] = 0.f;
    float S = 0.f;
    {
        const __hip_bfloat16* dtp = dtp0;
        const __hip_bfloat16* up = up0;
        __hip_bfloat16* yp = yp0;
#pragma unroll
        for (int k = 0; k < 16; ++k) {
            float dtv = __bfloat162float(*dtp); dtp += dstep;
            float uv  = __bfloat162float(*up);  up += ustep;
            S += dtv;
            float du = dtv * uv;
            float Bv[16], Cv[16], dec[16];
            unpack16(&Bs[(i0 + k) * 16], Bv);
            unpack16(&Cs[(i0 + k) * 16], Cv);
            if (fast) {
                float v1 = exp2f(dtv * A0c);
                dec[0] = v1;
#pragma unroll
                for (int s = 1; s < 16; ++s) dec[s] = dec[s - 1] * v1;
            } else {
#pragma unroll
                for (int s = 0; s < 16; ++s) dec[s] = exp2f(dtv * A2[s]);
            }
            float yl = uv * Dval;
#pragma unroll
            for (int s = 0; s < 16; ++s) {
                h[s] = dec[s] * h[s] + du * Bv[s];
                yl = fmaf(Cv[s], h[s], yl);
            }
            *yp = __float2bfloat16(yl); yp += dstep;
        }
    }
    // ---- write packed P|F ----
    {
        float w1 = fast ? exp2f(S * A0c) : 0.f;
        float pw = 1.f;
#pragma unroll
        for (int s = 0; s < 16; ++s) {
            float Pv;
            if (fast) { pw *= w1; Pv = pw; }
            else Pv = exp2f(A2[s] * S);
            unsigned wrd = (unsigned)(unsigned short)f2bf(Pv) |
                           ((unsigned)(unsigned short)f2bf(h[s]) << 16);
            PF[(s * 16 + cc) * 32 + dl] = wrd;
        }
    }
    __syncthreads();
    // ---- prefix over chunks (in place: Hin f32 overwrites packed slot) ----
    {
        int s2 = tid >> 5, dl2 = tid & 31;
        float hh = 0.f;
#pragma unroll
        for (int c2 = 0; c2 < 16; ++c2) {
            int idx = (s2 * 16 + c2) * 32 + dl2;
            unsigned wv = PF[idx];
            float pv = __uint_as_float(wv << 16);
            float fv = __uint_as_float(wv & 0xFFFF0000u);
            ((float*)PF)[idx] = hh;     // Hin for chunk c2
            hh = fv + pv * hh;
        }
    }
    __syncthreads();
    // ---- Pass B: y += correction ----
    {
        float q[16];
#pragma unroll
        for (int s = 0; s < 16; ++s) q[s] = ((float*)PF)[(s * 16 + cc) * 32 + dl];
        const __hip_bfloat16* dtp = dtp0;
        __hip_bfloat16* yp = yp0;
        float S2 = 0.f;
#pragma unroll
        for (int k = 0; k < 16; ++k) {
            float dtv = __bfloat162float(*dtp); dtp += dstep;
            S2 += dtv;
            float Cv[16];
            unpack16(&Cs[(i0 + k) * 16], Cv);
            float corr;
            if (fast) {
                float w1 = exp2f(S2 * A0c);
                float acc = Cv[15] * q[15];
#pragma unroll
                for (int s = 14; s >= 0; --s) acc = acc * w1 + Cv[s] * q[s];
                corr = acc * w1;
            } else {
                corr = 0.f;
#pragma unroll
                for (int s = 0; s < 16; ++s) corr += Cv[s] * q[s] * exp2f(A2[s] * S2);
            }
            float ycur = __bfloat162float(*yp);
            *yp = __float2bfloat16(ycur + corr);
            yp += dstep;
        }
    }
}

// ---------------- unpatchify ----------------
__global__ void unpatch(const float* __restrict__ tmp, float* __restrict__ out) {
    int i = blockIdx.x * blockDim.x + threadIdx.x;
    if (i >= 16 * 3 * 64 * 64) return;
    int b = i / (3 * 4096);
    int rem = i % (3 * 4096);
    int c = rem / 4096;
    int pos = rem % 4096;
    int hy = pos >> 6, wx = pos & 63;
    int l = (hy >> 2) * 16 + (wx >> 2);
    int jj = c * 16 + (hy & 3) * 4 + (wx & 3);
    out[i] = tmp[((size_t)b * 256 + l) * 48 + jj];
}

extern "C" void kernel_launch(void* const* d_in, const int* in_sizes, int n_in,
                              void* d_out, int out_size, void* d_ws, size_t ws_size,
                              hipStream_t stream) {
    const float* x        = (const float*)d_in[0];
    const int*   t        = (const int*)d_in[1];
    const float* patch_w  = (const float*)d_in[2];
    const float* patch_b  = (const float*)d_in[3];
    const float* tw1      = (const float*)d_in[4];
    const float* tb1      = (const float*)d_in[5];
    const float* tw2      = (const float*)d_in[6];
    const float* tb2      = (const float*)d_in[7];
    const float* norm_g   = (const float*)d_in[8];
    const float* norm_b   = (const float*)d_in[9];
    const float* inproj_w = (const float*)d_in[10];
    const float* conv_w   = (const float*)d_in[11];
    const float* conv_b   = (const float*)d_in[12];
    const float* Alog_f   = (const float*)d_in[13];
    const float* D_f      = (const float*)d_in[14];
    const float* xproj_f  = (const float*)d_in[15];
    const float* dtw_f    = (const float*)d_in[16];
    const float* dtb_f    = (const float*)d_in[17];
    const float* Alog_bk  = (const float*)d_in[18];
    const float* D_bk     = (const float*)d_in[19];
    const float* xproj_bk = (const float*)d_in[20];
    const float* dtw_bk   = (const float*)d_in[21];
    const float* dtb_bk   = (const float*)d_in[22];
    const float* outproj_w= (const float*)d_in[23];
    const float* fng      = (const float*)d_in[24];
    const float* fnb      = (const float*)d_in[25];
    const float* fin_w    = (const float*)d_in[26];
    const float* fin_b    = (const float*)d_in[27];
    float* out = (float*)d_out;

    char* base = (char*)d_ws;
    float*          te  = (float*)base;                                   // 16 KB
    float*          h   = (float*)(base + (16UL << 10));                  // 4 MB
    __hip_bfloat16* hn  = (__hip_bfloat16*)(base + (16UL << 10) + (4UL << 20));   // 2 MB
    __hip_bfloat16* xz  = (__hip_bfloat16*)((char*)hn + (2UL << 20));     // 8 MB
    __hip_bfloat16* uu  = (__hip_bfloat16*)((char*)xz + (8UL << 20));     // 4 MB
    float*          pf2 = (float*)((char*)uu + (4UL << 20));              // 2 MB
    __hip_bfloat16* dt2 = (__hip_bfloat16*)((char*)pf2 + (2UL << 20));    // 8 MB
    __hip_bfloat16* y2  = (__hip_bfloat16*)((char*)dt2 + (8UL << 20));    // 8 MB
    __hip_bfloat16* wbf = (__hip_bfloat16*)((char*)y2 + (8UL << 20));     // 4 MB
    float*          hnf = (float*)dt2;
    float*          htmp= pf2;

    __hip_bfloat16* w_in  = wbf;
    __hip_bfloat16* w_xf  = wbf + 1048576;
    __hip_bfloat16* w_xb  = wbf + 1179648;
    __hip_bfloat16* w_dtf = wbf + 1310720;
    __hip_bfloat16* w_dtb = wbf + 1376256;
    __hip_bfloat16* w_out = wbf + 1441792;

    const int M = BB * LL;                // 4096

    cvt_w<<<1920, 256, 0, stream>>>(inproj_w, xproj_f, xproj_bk, dtw_f, dtw_bk,
                                    outproj_w, wbf);
    patch_embed<<<256, 256, 0, stream>>>(x, patch_w, patch_b, h);
    time_embed<<<BB, 256, 0, stream>>>(t, tw1, tb1, tw2, tb2, te);

    for (int i = 0; i < 4; ++i) {
        ln_kernel<__hip_bfloat16><<<M, 256, 0, stream>>>(
            h, te, norm_g + i * 256, norm_b + i * 256, hn);
        gemm_mfma<128, 128, 2, 2, 4, 4, 0, false, false, 0, true><<<dim3(8, 32), 256, 0, stream>>>(
            hn, w_in + (size_t)i * 262144, nullptr, xz, M, 1024, 256, 256,
            nullptr, nullptr, nullptr, 0);
        conv_silu<<<1024, 256, 0, stream>>>(xz, conv_w + i * 2048, conv_b + i * 512, uu);
        gemm_mfma<32, 64, 2, 2, 1, 2, 0, false, false, 0, false><<<dim3(2, 128), 256, 0, stream>>>(
            uu, w_xf + (size_t)i * 32768, nullptr, pf2, M, 128, 512, 512,
            uu, w_xb + (size_t)i * 32768, nullptr, 64);
        gemm_mfma<128, 128, 2, 2, 4, 4, 1, false, true, 1, true><<<dim3(8, 32), 256, 0, stream>>>(
            pf2, w_dtf + (size_t)i * 16384, dtb_f + i * 512, dt2, M, 1024, 32, 128,
            pf2 + 64, w_dtb + (size_t)i * 16384, dtb_bk + i * 512, 512);
        scan_fused<<<512, 512, 0, stream>>>(uu, dt2, pf2,
            Alog_f + (size_t)i * 8192, Alog_bk + (size_t)i * 8192,
            D_f + i * 512, D_bk + i * 512, y2);
        gemm_mfma<64, 64, 4, 1, 1, 4, 0, true, false, 2, false><<<dim3(4, 64), 256, 0, stream>>>(
            y2, w_out + (size_t)i * 131072, nullptr, h, M, 256, 512, 1024,
            xz, nullptr, nullptr, 0);
    }

    ln_kernel<float><<<M, 256, 0, stream>>>(h, nullptr, fng, fnb, hnf);
    gemm_nt<0, false, true><<<dim3(1, 64), 256, 0, stream>>>(
        hnf, fin_w, fin_b, htmp, M, 48, 256, 256);
    unpatch<<<768, 256, 0, stream>>>(htmp, out);
}

// Round 8
// 538.952 us; speedup vs baseline: 1.2184x; 1.0415x over previous
//
#include <hip/hip_runtime.h>
#include <hip/hip_bf16.h>

#define BB 16
#define LL 256
#define DD 256
#define DI 512
#define DS 16

typedef __attribute__((ext_vector_type(8))) short bf16x8;
typedef __attribute__((ext_vector_type(4))) short bf16x4;
typedef __attribute__((ext_vector_type(4))) float f32x4;

__device__ inline short f2bf(float f) {
    __hip_bfloat16 h = __float2bfloat16(f);
    return *reinterpret_cast<short*>(&h);
}
__device__ inline float bf2f_s(short s) {
    __hip_bfloat16 h = *reinterpret_cast<__hip_bfloat16*>(&s);
    return __bfloat162float(h);
}
__device__ inline void stf(float* p, float v) { *p = v; }
__device__ inline void stf(__hip_bfloat16* p, float v) { *p = __float2bfloat16(v); }

// unpack 16 contiguous bf16 (32B, 16B-aligned) from LDS into 16 floats
__device__ inline void unpack16(const short* p, float* f) {
    bf16x8 v0 = *(const bf16x8*)p;
    bf16x8 v1 = *(const bf16x8*)(p + 8);
    const unsigned* a = (const unsigned*)&v0;
    const unsigned* b = (const unsigned*)&v1;
#pragma unroll
    for (int j = 0; j < 4; ++j) {
        f[2 * j]     = __uint_as_float(a[j] << 16);
        f[2 * j + 1] = __uint_as_float(a[j] & 0xFFFF0000u);
        f[8 + 2 * j]     = __uint_as_float(b[j] << 16);
        f[8 + 2 * j + 1] = __uint_as_float(b[j] & 0xFFFF0000u);
    }
}

// ---------------- weight fp32->bf16 pre-convert (once per call) ----------------
__global__ __launch_bounds__(256) void cvt_w(
    const float* __restrict__ s0, const float* __restrict__ s1,
    const float* __restrict__ s2, const float* __restrict__ s3,
    const float* __restrict__ s4, const float* __restrict__ s5,
    __hip_bfloat16* __restrict__ dst) {
    int i = blockIdx.x * 256 + threadIdx.x;      // vec4 index
    if (i >= 491520) return;
    int e = i * 4;
    const float* src; int off;
    if (e < 1048576)      { src = s0; off = e; }
    else if (e < 1179648) { src = s1; off = e - 1048576; }
    else if (e < 1310720) { src = s2; off = e - 1179648; }
    else if (e < 1376256) { src = s3; off = e - 1310720; }
    else if (e < 1441792) { src = s4; off = e - 1376256; }
    else                  { src = s5; off = e - 1441792; }
    float4 v = *(const float4*)(src + off);
    bf16x4 r;
    r[0] = f2bf(v.x); r[1] = f2bf(v.y); r[2] = f2bf(v.z); r[3] = f2bf(v.w);
    *(bf16x4*)((short*)dst + e) = r;
}

// ---------------- patch embed ----------------
__global__ __launch_bounds__(256) void patch_embed(const float* __restrict__ x,
                                                   const float* __restrict__ pw,
                                                   const float* __restrict__ pb,
                                                   float* __restrict__ h) {
    int blk = blockIdx.x;           // b*16 + lg
    int b = blk >> 4, lg = blk & 15;
    int tid = threadIdx.x;
    __shared__ float pws[48 * 258];
    __shared__ float xs[16][48];
    for (int it = 0; it < 48; ++it) {
        int idx = tid + it * 256;
        float v = pw[idx];
        int dd = idx / 48, k = idx - dd * 48;
        pws[k * 258 + dd] = v;
    }
    for (int idx = tid; idx < 16 * 48; idx += 256) {
        int li = idx / 48, k = idx - li * 48;
        int c = k >> 4, py = (k >> 2) & 3, px = k & 3;
        xs[li][k] = x[(size_t)(b * 3 + c) * 4096 + (lg * 4 + py) * 64 + li * 4 + px];
    }
    __syncthreads();
    float bv = pb[tid];
#pragma unroll 4
    for (int li = 0; li < 16; ++li) {
        float acc = bv;
#pragma unroll
        for (int k = 0; k < 48; ++k) acc += xs[li][k] * pws[k * 258 + tid];
        h[((size_t)(b * 256 + lg * 16 + li)) * 256 + tid] = acc;
    }
}

// ---------------- time embedding ----------------
__global__ void time_embed(const int* __restrict__ t, const float* __restrict__ tw1,
                           const float* __restrict__ tb1, const float* __restrict__ tw2,
                           const float* __restrict__ tb2, float* __restrict__ te) {
    int b = blockIdx.x, j = threadIdx.x;
    __shared__ float s0[256], s1[256];
    float tv = (float)t[b];
    if (j < 128) {
        float f = expf((float)j * (-9.210340371976184f / 127.f));
        float a = tv * f;
        s0[j] = sinf(a);
        s0[j + 128] = cosf(a);
    }
    __syncthreads();
    float acc = tb1[j];
    for (int k = 0; k < 256; ++k) acc += s0[k] * tw1[j * 256 + k];
    s1[j] = acc / (1.f + expf(-acc));
    __syncthreads();
    float acc2 = tb2[j];
    for (int k = 0; k < 256; ++k) acc2 += s1[k] * tw2[j * 256 + k];
    te[b * 256 + j] = acc2;
}

// ---------------- layernorm ----------------
template <typename TO>
__global__ void ln_kernel(const float* __restrict__ h, const float* __restrict__ te,
                          const float* __restrict__ g, const float* __restrict__ bta,
                          TO* __restrict__ out) {
    int row = blockIdx.x;
    int b = row >> 8;
    int d = threadIdx.x;
    float v = h[(size_t)row * 256 + d] + (te ? te[b * 256 + d] : 0.f);
    float s = v, s2 = v * v;
#pragma unroll
    for (int o = 32; o; o >>= 1) {
        s += __shfl_down(s, o, 64);
        s2 += __shfl_down(s2, o, 64);
    }
    __shared__ float ws[4], ws2[4];
    int wid = threadIdx.x >> 6, lane = threadIdx.x & 63;
    if (lane == 0) { ws[wid] = s; ws2[wid] = s2; }
    __syncthreads();
    float mu = (ws[0] + ws[1] + ws[2] + ws[3]) * (1.f / 256.f);
    float m2 = (ws2[0] + ws2[1] + ws2[2] + ws2[3]) * (1.f / 256.f);
    float var = m2 - mu * mu;
    stf(&out[(size_t)row * 256 + d], (v - mu) * rsqrtf(var + 1e-5f) * g[d] + bta[d]);
}

// ---------------- bf16 MFMA GEMM (bf16 weights) ----------------
// m-tile on blockIdx.x (XCD locality for A), n-tile on blockIdx.y.
template <int BM, int BN, int WM, int WN, int FM, int FN, int ACT, bool ADD,
          bool HASBIAS, int AMODE, bool OBF>
__global__ __launch_bounds__(256) void gemm_mfma(
    const void* __restrict__ Ap, const __hip_bfloat16* __restrict__ W,
    const float* __restrict__ bias, void* __restrict__ Cp,
    int M, int N, int K, int lda,
    const void* __restrict__ A2p, const __hip_bfloat16* __restrict__ W2,
    const float* __restrict__ bias2, int nsplit)
{
    constexpr int LDP = 40;
    __shared__ __align__(16) short As[BM * LDP];
    __shared__ __align__(16) short Ws[BN * LDP];
    int tid = threadIdx.x;
    int lane = tid & 63;
    int w = tid >> 6;
    int wm, wn;
    if (WN == 1) { wm = w; wn = 0; } else { wm = w >> 1; wn = w & 1; }
    int m0 = blockIdx.x * BM;
    int n0 = blockIdx.y * BN;
    int wn0 = n0;
    if (nsplit > 0 && n0 >= nsplit) { Ap = A2p; W = W2; bias = bias2; wn0 = n0 - nsplit; }

    f32x4 acc[FM][FN];
#pragma unroll
    for (int i = 0; i < FM; ++i)
#pragma unroll
        for (int j = 0; j < FN; ++j) acc[i][j] = (f32x4){0.f, 0.f, 0.f, 0.f};

    for (int k0 = 0; k0 < K; k0 += 32) {
        if (AMODE == 0) {
            for (int idx = tid; idx < BM * 4; idx += 256) {
                int row = idx >> 2, qc = idx & 3;
                const __hip_bfloat16* g = (const __hip_bfloat16*)Ap +
                    (size_t)(m0 + row) * lda + k0 + qc * 8;
                *(bf16x8*)&As[row * LDP + qc * 8] = *(const bf16x8*)g;
            }
        } else if (AMODE == 1) {
            for (int idx = tid; idx < BM * 4; idx += 256) {
                int row = idx >> 2, qc = idx & 3;
                const float* g = (const float*)Ap + (size_t)(m0 + row) * lda + k0 + qc * 8;
                float4 v0 = *(const float4*)g;
                float4 v1 = *(const float4*)(g + 4);
                union { bf16x8 v; short s[8]; } u8;
                u8.s[0] = f2bf(v0.x); u8.s[1] = f2bf(v0.y); u8.s[2] = f2bf(v0.z); u8.s[3] = f2bf(v0.w);
                u8.s[4] = f2bf(v1.x); u8.s[5] = f2bf(v1.y); u8.s[6] = f2bf(v1.z); u8.s[7] = f2bf(v1.w);
                *(bf16x8*)&As[row * LDP + qc * 8] = u8.v;
            }
        } else {
            for (int idx = tid; idx < BM * 4; idx += 256) {
                int row = idx >> 2, qc = idx & 3;
                size_t rb = (size_t)(m0 + row) * 1024 + k0 + qc * 8;
                union { bf16x8 v; short s[8]; } uf, ub, uz, r;
                uf.v = *(const bf16x8*)((const __hip_bfloat16*)Ap + rb);
                ub.v = *(const bf16x8*)((const __hip_bfloat16*)Ap + rb + 512);
                uz.v = *(const bf16x8*)((const __hip_bfloat16*)A2p + rb + 512);
#pragma unroll
                for (int e = 0; e < 8; ++e) {
                    float z = bf2f_s(uz.s[e]);
                    float sg = z / (1.f + __expf(-z));
                    r.s[e] = f2bf((bf2f_s(uf.s[e]) + bf2f_s(ub.s[e])) * sg);
                }
                *(bf16x8*)&As[row * LDP + qc * 8] = r.v;
            }
        }
        for (int idx = tid; idx < BN * 4; idx += 256) {
            int row = idx >> 2, qc = idx & 3;
            const __hip_bfloat16* g = W + (size_t)(wn0 + row) * K + k0 + qc * 8;
            *(bf16x8*)&Ws[row * LDP + qc * 8] = *(const bf16x8*)g;
        }
        __syncthreads();
        int kg = lane >> 4, r = lane & 15;
        bf16x8 af[FM], bfr[FN];
#pragma unroll
        for (int i = 0; i < FM; ++i)
            af[i] = *(const bf16x8*)&As[(wm * FM * 16 + i * 16 + r) * LDP + kg * 8];
#pragma unroll
        for (int j = 0; j < FN; ++j)
            bfr[j] = *(const bf16x8*)&Ws[(wn * FN * 16 + j * 16 + r) * LDP + kg * 8];
#pragma unroll
        for (int i = 0; i < FM; ++i)
#pragma unroll
            for (int j = 0; j < FN; ++j)
                acc[i][j] = __builtin_amdgcn_mfma_f32_16x16x32_bf16(af[i], bfr[j], acc[i][j], 0, 0, 0);
        __syncthreads();
    }
    int r = lane & 15, qg = lane >> 4;
#pragma unroll
    for (int i = 0; i < FM; ++i) {
#pragma unroll
        for (int j = 0; j < FN; ++j) {
            int col = n0 + wn * FN * 16 + j * 16 + r;
            int colw = wn0 + wn * FN * 16 + j * 16 + r;
            float bv = HASBIAS ? bias[colw] : 0.f;
#pragma unroll
            for (int q = 0; q < 4; ++q) {
                int rowm = m0 + wm * FM * 16 + i * 16 + qg * 4 + q;
                float v = acc[i][j][q] + bv;
                if (ACT == 1) v = (v > 20.f) ? v : log1pf(__expf(v));
                size_t o = (size_t)rowm * N + col;
                if (OBF) ((__hip_bfloat16*)Cp)[o] = __float2bfloat16(v);
                else if (ADD) ((float*)Cp)[o] += v;
                else ((float*)Cp)[o] = v;
            }
        }
    }
}

// ---------------- fp32 GEMM head (optionally fused unpatchify epilogue) ----------------
template <bool UNPATCH>
__global__ __launch_bounds__(256) void gemm_nt(const float* __restrict__ A,
                                               const float* __restrict__ W,
                                               const float* __restrict__ bias,
                                               float* __restrict__ C,
                                               int M, int N, int K, int lda) {
    __shared__ float Asm[16][65];
    __shared__ float Wsm[16][65];
    int tx = threadIdx.x & 15, ty = threadIdx.x >> 4;
    int m0 = blockIdx.x * 64, n0 = blockIdx.y * 64;
    float acc[4][4] = {};
    for (int k0 = 0; k0 < K; k0 += 16) {
#pragma unroll
        for (int i = 0; i < 4; ++i) {
            int idx = threadIdx.x + i * 256;
            int rr = idx >> 4, cc = idx & 15;
            Asm[cc][rr] = A[(size_t)(m0 + rr) * lda + k0 + cc];
            int n = n0 + rr;
            Wsm[cc][rr] = (n < N) ? W[(size_t)n * K + k0 + cc] : 0.f;
        }
        __syncthreads();
#pragma unroll
        for (int k = 0; k < 16; ++k) {
            float av[4], wv[4];
#pragma unroll
            for (int i = 0; i < 4; ++i) av[i] = Asm[k][ty * 4 + i];
#pragma unroll
            for (int j = 0; j < 4; ++j) wv[j] = Wsm[k][tx * 4 + j];
#pragma unroll
            for (int i = 0; i < 4; ++i)
#pragma unroll
                for (int j = 0; j < 4; ++j) acc[i][j] += av[i] * wv[j];
        }
        __syncthreads();
    }
#pragma unroll
    for (int i = 0; i < 4; ++i) {
        int m = m0 + ty * 4 + i;
#pragma unroll
        for (int j = 0; j < 4; ++j) {
            int n = n0 + tx * 4 + j;
            if (n < N) {
                float v = acc[i][j] + bias[n];
                if (UNPATCH) {
                    // out[b][c][hy][wx]: b=m>>8, l=m&255, c=n>>4, hy=(l>>4)*4+((n>>2)&3),
                    // wx=(l&15)*4+(n&3)
                    int b = m >> 8, l = m & 255;
                    int c = n >> 4;
                    int hy = ((l >> 4) << 2) + ((n >> 2) & 3);
                    int wx = ((l & 15) << 2) + (n & 3);
                    C[(size_t)(b * 3 + c) * 4096 + hy * 64 + wx] = v;
                } else {
                    C[(size_t)m * N + n] = v;
                }
            }
        }
    }
}

// ---------------- causal depthwise conv (k=4) + silu ----------------
__global__ __launch_bounds__(256) void conv_silu(
    const __hip_bfloat16* __restrict__ xz, const float* __restrict__ cw,
    const float* __restrict__ cb, __hip_bfloat16* __restrict__ u) {
    int g = blockIdx.x * 4 + (threadIdx.x >> 6);
    int lane = threadIdx.x & 63;
    int l = g & 255;
    int d0 = lane * 8;
    const __hip_bfloat16* base = xz + (size_t)g * 1024 + d0;
    union { bf16x8 v; short s[8]; } t0, t1, t2, t3, r;
    bf16x8 zz = {};
    t3.v = *(const bf16x8*)base;
    t2.v = (l >= 1) ? *(const bf16x8*)(base - 1024) : zz;
    t1.v = (l >= 2) ? *(const bf16x8*)(base - 2048) : zz;
    t0.v = (l >= 3) ? *(const bf16x8*)(base - 3072) : zz;
#pragma unroll
    for (int e = 0; e < 8; ++e) {
        int d = d0 + e;
        const float4 wv = *(const float4*)(cw + d * 4);
        float acc = cb[d] + bf2f_s(t0.s[e]) * wv.x + bf2f_s(t1.s[e]) * wv.y +
                    bf2f_s(t2.s[e]) * wv.z + bf2f_s(t3.s[e]) * wv.w;
        r.s[e] = f2bf(acc / (1.f + __expf(-acc)));
    }
    *(bf16x8*)(u + (size_t)g * 512 + d0) = r.v;
}

// ================= fused chunked SSM scan v6 =================
// 512 blocks, XCD-swizzled: all 16 dg-blocks of one (b,dir) on one XCD.
// 512 threads = 16 chunks x 32 channels.  Fast path (A[s]=(s+1)A[0], block-
// uniform vote): y_local + dt held in registers; y written ONCE in pass B.
__global__ __launch_bounds__(512, 4) void scan_fused(
    const __hip_bfloat16* __restrict__ u, const __hip_bfloat16* __restrict__ dt2,
    const float* __restrict__ pf2,
    const float* __restrict__ Alog_f, const float* __restrict__ Alog_b,
    const float* __restrict__ Dv_f, const float* __restrict__ Dv_b,
    __hip_bfloat16* __restrict__ y2)
{
    int blk = blockIdx.x;
    int c8 = blk & 7, idxb = blk >> 3;
    int bd = c8 + 8 * (idxb & 3);      // XCD swizzle: same bd -> same XCD
    int dg = idxb >> 2;
    int dir = bd & 1, b = bd >> 1;
    int tid = threadIdx.x;
    int dl = tid & 31, cc = tid >> 5;
    int d = dg * 32 + dl;
    int poff = dir ? 64 : 0;
    int doff = dir ? 512 : 0;
    const float* Alog = dir ? Alog_b : Alog_f;
    float Dval = (dir ? Dv_b : Dv_f)[d];

    __shared__ __align__(16) short Bs[256 * 16];   // 8 KB
    __shared__ __align__(16) short Cs[256 * 16];   // 8 KB
    __shared__ unsigned PF[16 * 16 * 32];          // 32 KB
    __shared__ int okflag;

    if (tid == 0) okflag = 1;
    for (int idx = tid; idx < 4096; idx += 512) {
        int i = idx >> 4, s = idx & 15;
        int tt = dir ? 255 - i : i;
        const float* pr = pf2 + ((size_t)b * 256 + tt) * 128 + poff;
        Bs[i * 16 + s] = f2bf(pr[32 + s]);
        Cs[i * 16 + s] = f2bf(pr[48 + s]);
    }
    float A2[16];
    {
        const float* ap = Alog + d * 16;
        float A0 = -__expf(ap[0]);
        bool okl = true;
#pragma unroll
        for (int s = 0; s < 16; ++s) {
            float As_ = -__expf(ap[s]);
            A2[s] = As_ * 1.44269504f;
            okl = okl && (fabsf(As_ - (float)(s + 1) * A0) <= 1e-3f * (float)(s + 1));
        }
        __syncthreads();          // okflag init + staging visible
        if (!okl) okflag = 0;
    }
    float A0c = A2[0];
    __syncthreads();
    bool fast = (okflag != 0);    // block-uniform

    int i0 = cc * 16;
    int row0 = b * 256 + (dir ? 255 - i0 : i0);
    int stpE = dir ? -1 : 1;
    int dstep = stpE * 1024, ustep = stpE * 512;
    const __hip_bfloat16* dtp0 = dt2 + (size_t)row0 * 1024 + doff + d;
    const __hip_bfloat16* up0  = u  + (size_t)row0 * 512 + d;
    __hip_bfloat16* yp0 = y2 + (size_t)row0 * 1024 + doff + d;

    float h[16], yl[16], dtv[16];
#pragma unroll
    for (int s = 0; s < 16; ++s) h[s] = 0.f;
    float S = 0.f;

    if (fast) {
        // ---- Pass A fast: local scan fully in registers ----
#pragma unroll
        for (int k = 0; k < 16; ++k) {
            float dt_ = __bfloat162float(dtp0[k * dstep]);
            float uv  = __bfloat162float(up0[k * ustep]);
            dtv[k] = dt_;
            S += dt_;
            float du = dt_ * uv;
            float Bv[16], Cv[16];
            unpack16(&Bs[(i0 + k) * 16], Bv);
            unpack16(&Cs[(i0 + k) * 16], Cv);
            float v1 = exp2f(dt_ * A0c);
            float yv = uv * Dval;
            float dec = v1;
#pragma unroll
            for (int s = 0; s < 16; ++s) {
                h[s] = dec * h[s] + du * Bv[s];
                yv = fmaf(Cv[s], h[s], yv);
                dec *= v1;
            }
            yl[k] = yv;
        }
        float w1 = exp2f(S * A0c);
        float pw = 1.f;
#pragma unroll
        for (int s = 0; s < 16; ++s) {
            pw *= w1;
            unsigned wrd = (unsigned)(unsigned short)f2bf(pw) |
                           ((unsigned)(unsigned short)f2bf(h[s]) << 16);
            PF[(s * 16 + cc) * 32 + dl] = wrd;
        }
    } else {
        // ---- Pass A generic (slow fallback; writes y_local to global) ----
        const __hip_bfloat16* dtp = dtp0;
        const __hip_bfloat16* up = up0;
        __hip_bfloat16* yp = yp0;
#pragma unroll
        for (int k = 0; k < 16; ++k) {
            float dt_ = __bfloat162float(*dtp); dtp += dstep;
            float uv  = __bfloat162float(*up);  up += ustep;
            S += dt_;
            float du = dt_ * uv;
            float Bv[16], Cv[16];
            unpack16(&Bs[(i0 + k) * 16], Bv);
            unpack16(&Cs[(i0 + k) * 16], Cv);
            float yv = uv * Dval;
#pragma unroll
            for (int s = 0; s < 16; ++s) {
                h[s] = exp2f(dt_ * A2[s]) * h[s] + du * Bv[s];
                yv = fmaf(Cv[s], h[s], yv);
            }
            *yp = __float2bfloat16(yv); yp += dstep;
        }
#pragma unroll
        for (int s = 0; s < 16; ++s) {
            float Pv = exp2f(A2[s] * S);
            unsigned wrd = (unsigned)(unsigned short)f2bf(Pv) |
                           ((unsigned)(unsigned short)f2bf(h[s]) << 16);
            PF[(s * 16 + cc) * 32 + dl] = wrd;
        }
    }
    __syncthreads();
    // ---- prefix over chunks (in place: Hin f32 overwrites packed slot) ----
    {
        int s2 = tid >> 5, dl2 = tid & 31;
        float hh = 0.f;
#pragma unroll
        for (int c2 = 0; c2 < 16; ++c2) {
            int idx = (s2 * 16 + c2) * 32 + dl2;
            unsigned wv = PF[idx];
            float pv = __uint_as_float(wv << 16);
            float fv = __uint_as_float(wv & 0xFFFF0000u);
            ((float*)PF)[idx] = hh;
            hh = fv + pv * hh;
        }
    }
    __syncthreads();
    // ---- Pass B ----
    float q[16];
#pragma unroll
    for (int s = 0; s < 16; ++s) q[s] = ((float*)PF)[(s * 16 + cc) * 32 + dl];
    if (fast) {
        float S2 = 0.f;
#pragma unroll
        for (int k = 0; k < 16; ++k) {
            S2 += dtv[k];
            float Cv[16];
            unpack16(&Cs[(i0 + k) * 16], Cv);
            float w1 = exp2f(S2 * A0c);
            float acc = Cv[15] * q[15];
#pragma unroll
            for (int s = 14; s >= 0; --s) acc = acc * w1 + Cv[s] * q[s];
            yp0[k * dstep] = __float2bfloat16(yl[k] + acc * w1);
        }
    } else {
        const __hip_bfloat16* dtp = dtp0;
        __hip_bfloat16* yp = yp0;
        float S2 = 0.f;
#pragma unroll
        for (int k = 0; k < 16; ++k) {
            float dt_ = __bfloat162float(*dtp); dtp += dstep;
            S2 += dt_;
            float Cv[16];
            unpack16(&Cs[(i0 + k) * 16], Cv);
            float corr = 0.f;
#pragma unroll
            for (int s = 0; s < 16; ++s) corr += Cv[s] * q[s] * exp2f(A2[s] * S2);
            float ycur = __bfloat162float(*yp);
            *yp = __float2bfloat16(ycur + corr);
            yp += dstep;
        }
    }
}

extern "C" void kernel_launch(void* const* d_in, const int* in_sizes, int n_in,
                              void* d_out, int out_size, void* d_ws, size_t ws_size,
                              hipStream_t stream) {
    const float* x        = (const float*)d_in[0];
    const int*   t        = (const int*)d_in[1];
    const float* patch_w  = (const float*)d_in[2];
    const float* patch_b  = (const float*)d_in[3];
    const float* tw1      = (const float*)d_in[4];
    const float* tb1      = (const float*)d_in[5];
    const float* tw2      = (const float*)d_in[6];
    const float* tb2      = (const float*)d_in[7];
    const float* norm_g   = (const float*)d_in[8];
    const float* norm_b   = (const float*)d_in[9];
    const float* inproj_w = (const float*)d_in[10];
    const float* conv_w   = (const float*)d_in[11];
    const float* conv_b   = (const float*)d_in[12];
    const float* Alog_f   = (const float*)d_in[13];
    const float* D_f      = (const float*)d_in[14];
    const float* xproj_f  = (const float*)d_in[15];
    const float* dtw_f    = (const float*)d_in[16];
    const float* dtb_f    = (const float*)d_in[17];
    const float* Alog_bk  = (const float*)d_in[18];
    const float* D_bk     = (const float*)d_in[19];
    const float* xproj_bk = (const float*)d_in[20];
    const float* dtw_bk   = (const float*)d_in[21];
    const float* dtb_bk   = (const float*)d_in[22];
    const float* outproj_w= (const float*)d_in[23];
    const float* fng      = (const float*)d_in[24];
    const float* fnb      = (const float*)d_in[25];
    const float* fin_w    = (const float*)d_in[26];
    const float* fin_b    = (const float*)d_in[27];
    float* out = (float*)d_out;

    char* base = (char*)d_ws;
    float*          te  = (float*)base;                                   // 16 KB
    float*          h   = (float*)(base + (16UL << 10));                  // 4 MB
    __hip_bfloat16* hn  = (__hip_bfloat16*)(base + (16UL << 10) + (4UL << 20));   // 2 MB
    __hip_bfloat16* xz  = (__hip_bfloat16*)((char*)hn + (2UL << 20));     // 8 MB
    __hip_bfloat16* uu  = (__hip_bfloat16*)((char*)xz + (8UL << 20));     // 4 MB
    float*          pf2 = (float*)((char*)uu + (4UL << 20));              // 2 MB
    __hip_bfloat16* dt2 = (__hip_bfloat16*)((char*)pf2 + (2UL << 20));    // 8 MB
    __hip_bfloat16* y2  = (__hip_bfloat16*)((char*)dt2 + (8UL << 20));    // 8 MB
    __hip_bfloat16* wbf = (__hip_bfloat16*)((char*)y2 + (8UL << 20));     // 4 MB
    float*          hnf = (float*)dt2;

    __hip_bfloat16* w_in  = wbf;
    __hip_bfloat16* w_xf  = wbf + 1048576;
    __hip_bfloat16* w_xb  = wbf + 1179648;
    __hip_bfloat16* w_dtf = wbf + 1310720;
    __hip_bfloat16* w_dtb = wbf + 1376256;
    __hip_bfloat16* w_out = wbf + 1441792;

    const int M = BB * LL;                // 4096

    cvt_w<<<1920, 256, 0, stream>>>(inproj_w, xproj_f, xproj_bk, dtw_f, dtw_bk,
                                    outproj_w, wbf);
    patch_embed<<<256, 256, 0, stream>>>(x, patch_w, patch_b, h);
    time_embed<<<BB, 256, 0, stream>>>(t, tw1, tb1, tw2, tb2, te);

    for (int i = 0; i < 4; ++i) {
        ln_kernel<__hip_bfloat16><<<M, 256, 0, stream>>>(
            h, te, norm_g + i * 256, norm_b + i * 256, hn);
        gemm_mfma<128, 128, 2, 2, 4, 4, 0, false, false, 0, true><<<dim3(32, 8), 256, 0, stream>>>(
            hn, w_in + (size_t)i * 262144, nullptr, xz, M, 1024, 256, 256,
            nullptr, nullptr, nullptr, 0);
        conv_silu<<<1024, 256, 0, stream>>>(xz, conv_w + i * 2048, conv_b + i * 512, uu);
        gemm_mfma<32, 64, 2, 2, 1, 2, 0, false, false, 0, false><<<dim3(128, 2), 256, 0, stream>>>(
            uu, w_xf + (size_t)i * 32768, nullptr, pf2, M, 128, 512, 512,
            uu, w_xb + (size_t)i * 32768, nullptr, 64);
        gemm_mfma<128, 128, 2, 2, 4, 4, 1, false, true, 1, true><<<dim3(32, 8), 256, 0, stream>>>(
            pf2, w_dtf + (size_t)i * 16384, dtb_f + i * 512, dt2, M, 1024, 32, 128,
            pf2 + 64, w_dtb + (size_t)i * 16384, dtb_bk + i * 512, 512);
        scan_fused<<<512, 512, 0, stream>>>(uu, dt2, pf2,
            Alog_f + (size_t)i * 8192, Alog_bk + (size_t)i * 8192,
            D_f + i * 512, D_bk + i * 512, y2);
        gemm_mfma<64, 64, 4, 1, 1, 4, 0, true, false, 2, false><<<dim3(64, 4), 256, 0, stream>>>(
            y2, w_out + (size_t)i * 131072, nullptr, h, M, 256, 512, 1024,
            xz, nullptr, nullptr, 0);
    }

    ln_kernel<float><<<M, 256, 0, stream>>>(h, nullptr, fng, fnb, hnf);
    gemm_nt<true><<<dim3(64, 1), 256, 0, stream>>>(
        hnf, fin_w, fin_b, out, M, 48, 256, 256);
}

// Round 9
// 481.653 us; speedup vs baseline: 1.3633x; 1.1190x over previous
//
#include <hip/hip_runtime.h>
#include <hip/hip_bf16.h>

#define BB 16
#define LL 256
#define DD 256
#define DI 512
#define DS 16

typedef __attribute__((ext_vector_type(8))) short bf16x8;
typedef __attribute__((ext_vector_type(4))) short bf16x4;
typedef __attribute__((ext_vector_type(4))) float f32x4;

__device__ inline short f2bf(float f) {
    __hip_bfloat16 h = __float2bfloat16(f);
    return *reinterpret_cast<short*>(&h);
}
__device__ inline float bf2f_s(short s) {
    __hip_bfloat16 h = *reinterpret_cast<__hip_bfloat16*>(&s);
    return __bfloat162float(h);
}
__device__ inline void stf(float* p, float v) { *p = v; }
__device__ inline void stf(__hip_bfloat16* p, float v) { *p = __float2bfloat16(v); }

// unpack 16 contiguous bf16 (32B, 16B-aligned) from LDS into 16 floats
__device__ inline void unpack16(const short* p, float* f) {
    bf16x8 v0 = *(const bf16x8*)p;
    bf16x8 v1 = *(const bf16x8*)(p + 8);
    const unsigned* a = (const unsigned*)&v0;
    const unsigned* b = (const unsigned*)&v1;
#pragma unroll
    for (int j = 0; j < 4; ++j) {
        f[2 * j]     = __uint_as_float(a[j] << 16);
        f[2 * j + 1] = __uint_as_float(a[j] & 0xFFFF0000u);
        f[8 + 2 * j]     = __uint_as_float(b[j] << 16);
        f[8 + 2 * j + 1] = __uint_as_float(b[j] & 0xFFFF0000u);
    }
}

// ---------------- weight fp32->bf16 pre-convert (once per call) ----------------
__global__ __launch_bounds__(256) void cvt_w(
    const float* __restrict__ s0, const float* __restrict__ s1,
    const float* __restrict__ s2, const float* __restrict__ s3,
    const float* __restrict__ s4, const float* __restrict__ s5,
    __hip_bfloat16* __restrict__ dst) {
    int i = blockIdx.x * 256 + threadIdx.x;      // vec4 index
    if (i >= 491520) return;
    int e = i * 4;
    const float* src; int off;
    if (e < 1048576)      { src = s0; off = e; }
    else if (e < 1179648) { src = s1; off = e - 1048576; }
    else if (e < 1310720) { src = s2; off = e - 1179648; }
    else if (e < 1376256) { src = s3; off = e - 1310720; }
    else if (e < 1441792) { src = s4; off = e - 1376256; }
    else                  { src = s5; off = e - 1441792; }
    float4 v = *(const float4*)(src + off);
    bf16x4 r;
    r[0] = f2bf(v.x); r[1] = f2bf(v.y); r[2] = f2bf(v.z); r[3] = f2bf(v.w);
    *(bf16x4*)((short*)dst + e) = r;
}

// ---------------- patch embed ----------------
__global__ __launch_bounds__(256) void patch_embed(const float* __restrict__ x,
                                                   const float* __restrict__ pw,
                                                   const float* __restrict__ pb,
                                                   float* __restrict__ h) {
    int blk = blockIdx.x;           // b*16 + lg
    int b = blk >> 4, lg = blk & 15;
    int tid = threadIdx.x;
    __shared__ float pws[48 * 258];
    __shared__ float xs[16][48];
    for (int it = 0; it < 48; ++it) {
        int idx = tid + it * 256;
        float v = pw[idx];
        int dd = idx / 48, k = idx - dd * 48;
        pws[k * 258 + dd] = v;
    }
    for (int idx = tid; idx < 16 * 48; idx += 256) {
        int li = idx / 48, k = idx - li * 48;
        int c = k >> 4, py = (k >> 2) & 3, px = k & 3;
        xs[li][k] = x[(size_t)(b * 3 + c) * 4096 + (lg * 4 + py) * 64 + li * 4 + px];
    }
    __syncthreads();
    float bv = pb[tid];
#pragma unroll 4
    for (int li = 0; li < 16; ++li) {
        float acc = bv;
#pragma unroll
        for (int k = 0; k < 48; ++k) acc += xs[li][k] * pws[k * 258 + tid];
        h[((size_t)(b * 256 + lg * 16 + li)) * 256 + tid] = acc;
    }
}

// ---------------- time embedding ----------------
__global__ void time_embed(const int* __restrict__ t, const float* __restrict__ tw1,
                           const float* __restrict__ tb1, const float* __restrict__ tw2,
                           const float* __restrict__ tb2, float* __restrict__ te) {
    int b = blockIdx.x, j = threadIdx.x;
    __shared__ float s0[256], s1[256];
    float tv = (float)t[b];
    if (j < 128) {
        float f = expf((float)j * (-9.210340371976184f / 127.f));
        float a = tv * f;
        s0[j] = sinf(a);
        s0[j + 128] = cosf(a);
    }
    __syncthreads();
    float acc = tb1[j];
    for (int k = 0; k < 256; ++k) acc += s0[k] * tw1[j * 256 + k];
    s1[j] = acc / (1.f + expf(-acc));
    __syncthreads();
    float acc2 = tb2[j];
    for (int k = 0; k < 256; ++k) acc2 += s1[k] * tw2[j * 256 + k];
    te[b * 256 + j] = acc2;
}

// ---------------- layernorm ----------------
template <typename TO>
__global__ void ln_kernel(const float* __restrict__ h, const float* __restrict__ te,
                          const float* __restrict__ g, const float* __restrict__ bta,
                          TO* __restrict__ out) {
    int row = blockIdx.x;
    int b = row >> 8;
    int d = threadIdx.x;
    float v = h[(size_t)row * 256 + d] + (te ? te[b * 256 + d] : 0.f);
    float s = v, s2 = v * v;
#pragma unroll
    for (int o = 32; o; o >>= 1) {
        s += __shfl_down(s, o, 64);
        s2 += __shfl_down(s2, o, 64);
    }
    __shared__ float ws[4], ws2[4];
    int wid = threadIdx.x >> 6, lane = threadIdx.x & 63;
    if (lane == 0) { ws[wid] = s; ws2[wid] = s2; }
    __syncthreads();
    float mu = (ws[0] + ws[1] + ws[2] + ws[3]) * (1.f / 256.f);
    float m2 = (ws2[0] + ws2[1] + ws2[2] + ws2[3]) * (1.f / 256.f);
    float var = m2 - mu * mu;
    stf(&out[(size_t)row * 256 + d], (v - mu) * rsqrtf(var + 1e-5f) * g[d] + bta[d]);
}

// ---------------- bf16 MFMA GEMM (bf16 weights) ----------------
template <int BM, int BN, int WM, int WN, int FM, int FN, int ACT, bool ADD,
          bool HASBIAS, int AMODE, bool OBF>
__global__ __launch_bounds__(256) void gemm_mfma(
    const void* __restrict__ Ap, const __hip_bfloat16* __restrict__ W,
    const float* __restrict__ bias, void* __restrict__ Cp,
    int M, int N, int K, int lda,
    const void* __restrict__ A2p, const __hip_bfloat16* __restrict__ W2,
    const float* __restrict__ bias2, int nsplit)
{
    constexpr int LDP = 40;
    __shared__ __align__(16) short As[BM * LDP];
    __shared__ __align__(16) short Ws[BN * LDP];
    int tid = threadIdx.x;
    int lane = tid & 63;
    int w = tid >> 6;
    int wm, wn;
    if (WN == 1) { wm = w; wn = 0; } else { wm = w >> 1; wn = w & 1; }
    int m0 = blockIdx.x * BM;
    int n0 = blockIdx.y * BN;
    int wn0 = n0;
    if (nsplit > 0 && n0 >= nsplit) { Ap = A2p; W = W2; bias = bias2; wn0 = n0 - nsplit; }

    f32x4 acc[FM][FN];
#pragma unroll
    for (int i = 0; i < FM; ++i)
#pragma unroll
        for (int j = 0; j < FN; ++j) acc[i][j] = (f32x4){0.f, 0.f, 0.f, 0.f};

    for (int k0 = 0; k0 < K; k0 += 32) {
        if (AMODE == 0) {
            for (int idx = tid; idx < BM * 4; idx += 256) {
                int row = idx >> 2, qc = idx & 3;
                const __hip_bfloat16* g = (const __hip_bfloat16*)Ap +
                    (size_t)(m0 + row) * lda + k0 + qc * 8;
                *(bf16x8*)&As[row * LDP + qc * 8] = *(const bf16x8*)g;
            }
        } else if (AMODE == 1) {
            for (int idx = tid; idx < BM * 4; idx += 256) {
                int row = idx >> 2, qc = idx & 3;
                const float* g = (const float*)Ap + (size_t)(m0 + row) * lda + k0 + qc * 8;
                float4 v0 = *(const float4*)g;
                float4 v1 = *(const float4*)(g + 4);
                union { bf16x8 v; short s[8]; } u8;
                u8.s[0] = f2bf(v0.x); u8.s[1] = f2bf(v0.y); u8.s[2] = f2bf(v0.z); u8.s[3] = f2bf(v0.w);
                u8.s[4] = f2bf(v1.x); u8.s[5] = f2bf(v1.y); u8.s[6] = f2bf(v1.z); u8.s[7] = f2bf(v1.w);
                *(bf16x8*)&As[row * LDP + qc * 8] = u8.v;
            }
        } else {
            for (int idx = tid; idx < BM * 4; idx += 256) {
                int row = idx >> 2, qc = idx & 3;
                size_t rb = (size_t)(m0 + row) * 1024 + k0 + qc * 8;
                union { bf16x8 v; short s[8]; } uf, ub, uz, r;
                uf.v = *(const bf16x8*)((const __hip_bfloat16*)Ap + rb);
                ub.v = *(const bf16x8*)((const __hip_bfloat16*)Ap + rb + 512);
                uz.v = *(const bf16x8*)((const __hip_bfloat16*)A2p + rb + 512);
#pragma unroll
                for (int e = 0; e < 8; ++e) {
                    float z = bf2f_s(uz.s[e]);
                    float sg = z / (1.f + __expf(-z));
                    r.s[e] = f2bf((bf2f_s(uf.s[e]) + bf2f_s(ub.s[e])) * sg);
                }
                *(bf16x8*)&As[row * LDP + qc * 8] = r.v;
            }
        }
        for (int idx = tid; idx < BN * 4; idx += 256) {
            int row = idx >> 2, qc = idx & 3;
            const __hip_bfloat16* g = W + (size_t)(wn0 + row) * K + k0 + qc * 8;
            *(bf16x8*)&Ws[row * LDP + qc * 8] = *(const bf16x8*)g;
        }
        __syncthreads();
        int kg = lane >> 4, r = lane & 15;
        bf16x8 af[FM], bfr[FN];
#pragma unroll
        for (int i = 0; i < FM; ++i)
            af[i] = *(const bf16x8*)&As[(wm * FM * 16 + i * 16 + r) * LDP + kg * 8];
#pragma unroll
        for (int j = 0; j < FN; ++j)
            bfr[j] = *(const bf16x8*)&Ws[(wn * FN * 16 + j * 16 + r) * LDP + kg * 8];
#pragma unroll
        for (int i = 0; i < FM; ++i)
#pragma unroll
            for (int j = 0; j < FN; ++j)
                acc[i][j] = __builtin_amdgcn_mfma_f32_16x16x32_bf16(af[i], bfr[j], acc[i][j], 0, 0, 0);
        __syncthreads();
    }
    int r = lane & 15, qg = lane >> 4;
#pragma unroll
    for (int i = 0; i < FM; ++i) {
#pragma unroll
        for (int j = 0; j < FN; ++j) {
            int col = n0 + wn * FN * 16 + j * 16 + r;
            int colw = wn0 + wn * FN * 16 + j * 16 + r;
            float bv = HASBIAS ? bias[colw] : 0.f;
#pragma unroll
            for (int q = 0; q < 4; ++q) {
                int rowm = m0 + wm * FM * 16 + i * 16 + qg * 4 + q;
                float v = acc[i][j][q] + bv;
                if (ACT == 1) v = (v > 20.f) ? v : log1pf(__expf(v));
                size_t o = (size_t)rowm * N + col;
                if (OBF) ((__hip_bfloat16*)Cp)[o] = __float2bfloat16(v);
                else if (ADD) ((float*)Cp)[o] += v;
                else ((float*)Cp)[o] = v;
            }
        }
    }
}

// ---------------- fp32 GEMM head (fused unpatchify epilogue) ----------------
template <bool UNPATCH>
__global__ __launch_bounds__(256) void gemm_nt(const float* __restrict__ A,
                                               const float* __restrict__ W,
                                               const float* __restrict__ bias,
                                               float* __restrict__ C,
                                               int M, int N, int K, int lda) {
    __shared__ float Asm[16][65];
    __shared__ float Wsm[16][65];
    int tx = threadIdx.x & 15, ty = threadIdx.x >> 4;
    int m0 = blockIdx.x * 64, n0 = blockIdx.y * 64;
    float acc[4][4] = {};
    for (int k0 = 0; k0 < K; k0 += 16) {
#pragma unroll
        for (int i = 0; i < 4; ++i) {
            int idx = threadIdx.x + i * 256;
            int rr = idx >> 4, cc = idx & 15;
            Asm[cc][rr] = A[(size_t)(m0 + rr) * lda + k0 + cc];
            int n = n0 + rr;
            Wsm[cc][rr] = (n < N) ? W[(size_t)n * K + k0 + cc] : 0.f;
        }
        __syncthreads();
#pragma unroll
        for (int k = 0; k < 16; ++k) {
            float av[4], wv[4];
#pragma unroll
            for (int i = 0; i < 4; ++i) av[i] = Asm[k][ty * 4 + i];
#pragma unroll
            for (int j = 0; j < 4; ++j) wv[j] = Wsm[k][tx * 4 + j];
#pragma unroll
            for (int i = 0; i < 4; ++i)
#pragma unroll
                for (int j = 0; j < 4; ++j) acc[i][j] += av[i] * wv[j];
        }
        __syncthreads();
    }
#pragma unroll
    for (int i = 0; i < 4; ++i) {
        int m = m0 + ty * 4 + i;
#pragma unroll
        for (int j = 0; j < 4; ++j) {
            int n = n0 + tx * 4 + j;
            if (n < N) {
                float v = acc[i][j] + bias[n];
                if (UNPATCH) {
                    int b = m >> 8, l = m & 255;
                    int c = n >> 4;
                    int hy = ((l >> 4) << 2) + ((n >> 2) & 3);
                    int wx = ((l & 15) << 2) + (n & 3);
                    C[(size_t)(b * 3 + c) * 4096 + hy * 64 + wx] = v;
                } else {
                    C[(size_t)m * N + n] = v;
                }
            }
        }
    }
}

// ---------------- causal depthwise conv (k=4) + silu ----------------
__global__ __launch_bounds__(256) void conv_silu(
    const __hip_bfloat16* __restrict__ xz, const float* __restrict__ cw,
    const float* __restrict__ cb, __hip_bfloat16* __restrict__ u) {
    int g = blockIdx.x * 4 + (threadIdx.x >> 6);
    int lane = threadIdx.x & 63;
    int l = g & 255;
    int d0 = lane * 8;
    const __hip_bfloat16* base = xz + (size_t)g * 1024 + d0;
    union { bf16x8 v; short s[8]; } t0, t1, t2, t3, r;
    bf16x8 zz = {};
    t3.v = *(const bf16x8*)base;
    t2.v = (l >= 1) ? *(const bf16x8*)(base - 1024) : zz;
    t1.v = (l >= 2) ? *(const bf16x8*)(base - 2048) : zz;
    t0.v = (l >= 3) ? *(const bf16x8*)(base - 3072) : zz;
#pragma unroll
    for (int e = 0; e < 8; ++e) {
        int d = d0 + e;
        const float4 wv = *(const float4*)(cw + d * 4);
        float acc = cb[d] + bf2f_s(t0.s[e]) * wv.x + bf2f_s(t1.s[e]) * wv.y +
                    bf2f_s(t2.s[e]) * wv.z + bf2f_s(t3.s[e]) * wv.w;
        r.s[e] = f2bf(acc / (1.f + __expf(-acc)));
    }
    *(bf16x8*)(u + (size_t)g * 512 + d0) = r.v;
}

// ================= fused chunked SSM scan v7 =================
// 512 blocks (XCD-swizzled), 512 threads = 16 chunks x 32 channels.
// Fast path (A[s]=(s+1)A[0], block-uniform vote): per-step decay v1k kept in
// registers; y written ONCE.  No launch_bounds min-occupancy clamp (r8 lesson:
// (512,4) forced VGPR=64 -> full spill, 81 MB scratch writes).
__global__ __launch_bounds__(512) void scan_fused(
    const __hip_bfloat16* __restrict__ u, const __hip_bfloat16* __restrict__ dt2,
    const float* __restrict__ pf2,
    const float* __restrict__ Alog_f, const float* __restrict__ Alog_b,
    const float* __restrict__ Dv_f, const float* __restrict__ Dv_b,
    __hip_bfloat16* __restrict__ y2)
{
    int blk = blockIdx.x;
    int c8 = blk & 7, idxb = blk >> 3;
    int bd = c8 + 8 * (idxb & 3);      // XCD swizzle: same bd -> same XCD
    int dg = idxb >> 2;
    int dir = bd & 1, b = bd >> 1;
    int tid = threadIdx.x;
    int dl = tid & 31, cc = tid >> 5;
    int d = dg * 32 + dl;
    int poff = dir ? 64 : 0;
    int doff = dir ? 512 : 0;
    const float* Alog = dir ? Alog_b : Alog_f;
    float Dval = (dir ? Dv_b : Dv_f)[d];

    __shared__ __align__(16) short Bs[256 * 16];   // 8 KB
    __shared__ __align__(16) short Cs[256 * 16];   // 8 KB
    __shared__ unsigned PF[16 * 16 * 32];          // 32 KB
    __shared__ int okflag;

    if (tid == 0) okflag = 1;
    for (int idx = tid; idx < 4096; idx += 512) {
        int i = idx >> 4, s = idx & 15;
        int tt = dir ? 255 - i : i;
        const float* pr = pf2 + ((size_t)b * 256 + tt) * 128 + poff;
        Bs[i * 16 + s] = f2bf(pr[32 + s]);
        Cs[i * 16 + s] = f2bf(pr[48 + s]);
    }
    float A0c;   // A[0]*log2e
    {
        const float* ap = Alog + d * 16;
        float A0 = -__expf(ap[0]);
        A0c = A0 * 1.44269504f;
        bool okl = true;
#pragma unroll
        for (int s = 1; s < 16; ++s) {
            float As_ = -__expf(ap[s]);
            okl = okl && (fabsf(As_ - (float)(s + 1) * A0) <= 1e-3f * (float)(s + 1));
        }
        __syncthreads();          // okflag init + staging visible
        if (!okl) okflag = 0;
    }
    __syncthreads();
    bool fast = (okflag != 0);    // block-uniform

    int i0 = cc * 16;
    int row0 = b * 256 + (dir ? 255 - i0 : i0);
    int stpE = dir ? -1 : 1;
    int dstep = stpE * 1024, ustep = stpE * 512;
    const __hip_bfloat16* dtp0 = dt2 + (size_t)row0 * 1024 + doff + d;
    const __hip_bfloat16* up0  = u  + (size_t)row0 * 512 + d;
    __hip_bfloat16* yp0 = y2 + (size_t)row0 * 1024 + doff + d;

    if (fast) {
        float h[16], yl[16], v1k[16];
#pragma unroll
        for (int s = 0; s < 16; ++s) h[s] = 0.f;
        // ---- Pass A: local scan fully in registers ----
#pragma unroll
        for (int k = 0; k < 16; ++k) {
            float dt_ = __bfloat162float(dtp0[k * dstep]);
            float uv  = __bfloat162float(up0[k * ustep]);
            float du = dt_ * uv;
            float Bv[16], Cv[16];
            unpack16(&Bs[(i0 + k) * 16], Bv);
            unpack16(&Cs[(i0 + k) * 16], Cv);
            float v1 = exp2f(dt_ * A0c);
            v1k[k] = v1;
            float yv = uv * Dval;
            float dec = v1;
#pragma unroll
            for (int s = 0; s < 16; ++s) {
                h[s] = dec * h[s] + du * Bv[s];
                yv = fmaf(Cv[s], h[s], yv);
                dec *= v1;
            }
            yl[k] = yv;
        }
        // chunk decay W = prod v1k; P[s] = W^(s+1)
        float W = v1k[0];
#pragma unroll
        for (int k = 1; k < 16; ++k) W *= v1k[k];
        float pw = 1.f;
#pragma unroll
        for (int s = 0; s < 16; ++s) {
            pw *= W;
            unsigned wrd = (unsigned)(unsigned short)f2bf(pw) |
                           ((unsigned)(unsigned short)f2bf(h[s]) << 16);
            PF[(s * 16 + cc) * 32 + dl] = wrd;
        }
        __syncthreads();
        // ---- prefix over chunks ----
        {
            int s2 = tid >> 5, dl2 = tid & 31;
            float hh = 0.f;
#pragma unroll
            for (int c2 = 0; c2 < 16; ++c2) {
                int idx = (s2 * 16 + c2) * 32 + dl2;
                unsigned wv = PF[idx];
                float pv = __uint_as_float(wv << 16);
                float fv = __uint_as_float(wv & 0xFFFF0000u);
                ((float*)PF)[idx] = hh;
                hh = fv + pv * hh;
            }
        }
        __syncthreads();
        // ---- Pass B: single y write ----
        float q[16];
#pragma unroll
        for (int s = 0; s < 16; ++s) q[s] = ((float*)PF)[(s * 16 + cc) * 32 + dl];
        float w1 = 1.f;
#pragma unroll
        for (int k = 0; k < 16; ++k) {
            w1 *= v1k[k];                 // = exp2(S2 * A0c)
            float Cv[16];
            unpack16(&Cs[(i0 + k) * 16], Cv);
            float acc = Cv[15] * q[15];
#pragma unroll
            for (int s = 14; s >= 0; --s) acc = acc * w1 + Cv[s] * q[s];
            yp0[k * dstep] = __float2bfloat16(yl[k] + acc * w1);
        }
    } else {
        // ---- generic fallback (never taken for this data; correctness path) ----
        float A2[16];
        {
            const float* ap = Alog + d * 16;
#pragma unroll
            for (int s = 0; s < 16; ++s) A2[s] = -__expf(ap[s]) * 1.44269504f;
        }
        float h[16];
#pragma unroll
        for (int s = 0; s < 16; ++s) h[s] = 0.f;
        float S = 0.f;
        {
            const __hip_bfloat16* dtp = dtp0;
            const __hip_bfloat16* up = up0;
            __hip_bfloat16* yp = yp0;
#pragma unroll
            for (int k = 0; k < 16; ++k) {
                float dt_ = __bfloat162float(*dtp); dtp += dstep;
                float uv  = __bfloat162float(*up);  up += ustep;
                S += dt_;
                float du = dt_ * uv;
                float Bv[16], Cv[16];
                unpack16(&Bs[(i0 + k) * 16], Bv);
                unpack16(&Cs[(i0 + k) * 16], Cv);
                float yv = uv * Dval;
#pragma unroll
                for (int s = 0; s < 16; ++s) {
                    h[s] = exp2f(dt_ * A2[s]) * h[s] + du * Bv[s];
                    yv = fmaf(Cv[s], h[s], yv);
                }
                *yp = __float2bfloat16(yv); yp += dstep;
            }
        }
#pragma unroll
        for (int s = 0; s < 16; ++s) {
            float Pv = exp2f(A2[s] * S);
            unsigned wrd = (unsigned)(unsigned short)f2bf(Pv) |
                           ((unsigned)(unsigned short)f2bf(h[s]) << 16);
            PF[(s * 16 + cc) * 32 + dl] = wrd;
        }
        __syncthreads();
        {
            int s2 = tid >> 5, dl2 = tid & 31;
            float hh = 0.f;
#pragma unroll
            for (int c2 = 0; c2 < 16; ++c2) {
                int idx = (s2 * 16 + c2) * 32 + dl2;
                unsigned wv = PF[idx];
                float pv = __uint_as_float(wv << 16);
                float fv = __uint_as_float(wv & 0xFFFF0000u);
                ((float*)PF)[idx] = hh;
                hh = fv + pv * hh;
            }
        }
        __syncthreads();
        float q[16];
#pragma unroll
        for (int s = 0; s < 16; ++s) q[s] = ((float*)PF)[(s * 16 + cc) * 32 + dl];
        const __hip_bfloat16* dtp = dtp0;
        __hip_bfloat16* yp = yp0;
        float S2 = 0.f;
#pragma unroll
        for (int k = 0; k < 16; ++k) {
            float dt_ = __bfloat162float(*dtp); dtp += dstep;
            S2 += dt_;
            float Cv[16];
            unpack16(&Cs[(i0 + k) * 16], Cv);
            float corr = 0.f;
#pragma unroll
            for (int s = 0; s < 16; ++s) corr += Cv[s] * q[s] * exp2f(A2[s] * S2);
            float ycur = __bfloat162float(*yp);
            *yp = __float2bfloat16(ycur + corr);
            yp += dstep;
        }
    }
}

extern "C" void kernel_launch(void* const* d_in, const int* in_sizes, int n_in,
                              void* d_out, int out_size, void* d_ws, size_t ws_size,
                              hipStream_t stream) {
    const float* x        = (const float*)d_in[0];
    const int*   t        = (const int*)d_in[1];
    const float* patch_w  = (const float*)d_in[2];
    const float* patch_b  = (const float*)d_in[3];
    const float* tw1      = (const float*)d_in[4];
    const float* tb1      = (const float*)d_in[5];
    const float* tw2      = (const float*)d_in[6];
    const float* tb2      = (const float*)d_in[7];
    const float* norm_g   = (const float*)d_in[8];
    const float* norm_b   = (const float*)d_in[9];
    const float* inproj_w = (const float*)d_in[10];
    const float* conv_w   = (const float*)d_in[11];
    const float* conv_b   = (const float*)d_in[12];
    const float* Alog_f   = (const float*)d_in[13];
    const float* D_f      = (const float*)d_in[14];
    const float* xproj_f  = (const float*)d_in[15];
    const float* dtw_f    = (const float*)d_in[16];
    const float* dtb_f    = (const float*)d_in[17];
    const float* Alog_bk  = (const float*)d_in[18];
    const float* D_bk     = (const float*)d_in[19];
    const float* xproj_bk = (const float*)d_in[20];
    const float* dtw_bk   = (const float*)d_in[21];
    const float* dtb_bk   = (const float*)d_in[22];
    const float* outproj_w= (const float*)d_in[23];
    const float* fng      = (const float*)d_in[24];
    const float* fnb      = (const float*)d_in[25];
    const float* fin_w    = (const float*)d_in[26];
    const float* fin_b    = (const float*)d_in[27];
    float* out = (float*)d_out;

    char* base = (char*)d_ws;
    float*          te  = (float*)base;                                   // 16 KB
    float*          h   = (float*)(base + (16UL << 10));                  // 4 MB
    __hip_bfloat16* hn  = (__hip_bfloat16*)(base + (16UL << 10) + (4UL << 20));   // 2 MB
    __hip_bfloat16* xz  = (__hip_bfloat16*)((char*)hn + (2UL << 20));     // 8 MB
    __hip_bfloat16* uu  = (__hip_bfloat16*)((char*)xz + (8UL << 20));     // 4 MB
    float*          pf2 = (float*)((char*)uu + (4UL << 20));              // 2 MB
    __hip_bfloat16* dt2 = (__hip_bfloat16*)((char*)pf2 + (2UL << 20));    // 8 MB
    __hip_bfloat16* y2  = (__hip_bfloat16*)((char*)dt2 + (8UL << 20));    // 8 MB
    __hip_bfloat16* wbf = (__hip_bfloat16*)((char*)y2 + (8UL << 20));     // 4 MB
    float*          hnf = (float*)dt2;

    __hip_bfloat16* w_in  = wbf;
    __hip_bfloat16* w_xf  = wbf + 1048576;
    __hip_bfloat16* w_xb  = wbf + 1179648;
    __hip_bfloat16* w_dtf = wbf + 1310720;
    __hip_bfloat16* w_dtb = wbf + 1376256;
    __hip_bfloat16* w_out = wbf + 1441792;

    const int M = BB * LL;                // 4096

    cvt_w<<<1920, 256, 0, stream>>>(inproj_w, xproj_f, xproj_bk, dtw_f, dtw_bk,
                                    outproj_w, wbf);
    patch_embed<<<256, 256, 0, stream>>>(x, patch_w, patch_b, h);
    time_embed<<<BB, 256, 0, stream>>>(t, tw1, tb1, tw2, tb2, te);

    for (int i = 0; i < 4; ++i) {
        ln_kernel<__hip_bfloat16><<<M, 256, 0, stream>>>(
            h, te, norm_g + i * 256, norm_b + i * 256, hn);
        gemm_mfma<128, 128, 2, 2, 4, 4, 0, false, false, 0, true><<<dim3(32, 8), 256, 0, stream>>>(
            hn, w_in + (size_t)i * 262144, nullptr, xz, M, 1024, 256, 256,
            nullptr, nullptr, nullptr, 0);
        conv_silu<<<1024, 256, 0, stream>>>(xz, conv_w + i * 2048, conv_b + i * 512, uu);
        gemm_mfma<32, 64, 2, 2, 1, 2, 0, false, false, 0, false><<<dim3(128, 2), 256, 0, stream>>>(
            uu, w_xf + (size_t)i * 32768, nullptr, pf2, M, 128, 512, 512,
            uu, w_xb + (size_t)i * 32768, nullptr, 64);
        gemm_mfma<128, 128, 2, 2, 4, 4, 1, false, true, 1, true><<<dim3(32, 8), 256, 0, stream>>>(
            pf2, w_dtf + (size_t)i * 16384, dtb_f + i * 512, dt2, M, 1024, 32, 128,
            pf2 + 64, w_dtb + (size_t)i * 16384, dtb_bk + i * 512, 512);
        scan_fused<<<512, 512, 0, stream>>>(uu, dt2, pf2,
            Alog_f + (size_t)i * 8192, Alog_bk + (size_t)i * 8192,
            D_f + i * 512, D_bk + i * 512, y2);
        gemm_mfma<64, 64, 4, 1, 1, 4, 0, true, false, 2, false><<<dim3(64, 4), 256, 0, stream>>>(
            y2, w_out + (size_t)i * 131072, nullptr, h, M, 256, 512, 1024,
            xz, nullptr, nullptr, 0);
    }

    ln_kernel<float><<<M, 256, 0, stream>>>(h, nullptr, fng, fnb, hnf);
    gemm_nt<true><<<dim3(64, 1), 256, 0, stream>>>(
        hnf, fin_w, fin_b, out, M, 48, 256, 256);
}

// Round 10
// 455.647 us; speedup vs baseline: 1.4412x; 1.0571x over previous
//
#include <hip/hip_runtime.h>
#include <hip/hip_bf16.h>

#define BB 16
#define LL 256
#define DD 256
#define DI 512
#define DS 16

typedef __attribute__((ext_vector_type(8))) short bf16x8;
typedef __attribute__((ext_vector_type(4))) short bf16x4;
typedef __attribute__((ext_vector_type(4))) float f32x4;

__device__ inline short f2bf(float f) {
    __hip_bfloat16 h = __float2bfloat16(f);
    return *reinterpret_cast<short*>(&h);
}
__device__ inline float bf2f_s(short s) {
    __hip_bfloat16 h = *reinterpret_cast<__hip_bfloat16*>(&s);
    return __bfloat162float(h);
}
__device__ inline void stf(float* p, float v) { *p = v; }
__device__ inline void stf(__hip_bfloat16* p, float v) { *p = __float2bfloat16(v); }

// unpack 16 contiguous bf16 (32B, 16B-aligned) from LDS into 16 floats
__device__ inline void unpack16(const short* p, float* f) {
    bf16x8 v0 = *(const bf16x8*)p;
    bf16x8 v1 = *(const bf16x8*)(p + 8);
    const unsigned* a = (const unsigned*)&v0;
    const unsigned* b = (const unsigned*)&v1;
#pragma unroll
    for (int j = 0; j < 4; ++j) {
        f[2 * j]     = __uint_as_float(a[j] << 16);
        f[2 * j + 1] = __uint_as_float(a[j] & 0xFFFF0000u);
        f[8 + 2 * j]     = __uint_as_float(b[j] << 16);
        f[8 + 2 * j + 1] = __uint_as_float(b[j] & 0xFFFF0000u);
    }
}

// ---------------- weight fp32->bf16 pre-convert (once per call) ----------------
__global__ __launch_bounds__(256) void cvt_w(
    const float* __restrict__ s0, const float* __restrict__ s1,
    const float* __restrict__ s2, const float* __restrict__ s3,
    const float* __restrict__ s4, const float* __restrict__ s5,
    __hip_bfloat16* __restrict__ dst) {
    int i = blockIdx.x * 256 + threadIdx.x;      // vec4 index
    if (i >= 491520) return;
    int e = i * 4;
    const float* src; int off;
    if (e < 1048576)      { src = s0; off = e; }
    else if (e < 1179648) { src = s1; off = e - 1048576; }
    else if (e < 1310720) { src = s2; off = e - 1179648; }
    else if (e < 1376256) { src = s3; off = e - 1310720; }
    else if (e < 1441792) { src = s4; off = e - 1376256; }
    else                  { src = s5; off = e - 1441792; }
    float4 v = *(const float4*)(src + off);
    bf16x4 r;
    r[0] = f2bf(v.x); r[1] = f2bf(v.y); r[2] = f2bf(v.z); r[3] = f2bf(v.w);
    *(bf16x4*)((short*)dst + e) = r;
}

// ---------------- patch embed ----------------
__global__ __launch_bounds__(256) void patch_embed(const float* __restrict__ x,
                                                   const float* __restrict__ pw,
                                                   const float* __restrict__ pb,
                                                   float* __restrict__ h) {
    int blk = blockIdx.x;           // b*16 + lg
    int b = blk >> 4, lg = blk & 15;
    int tid = threadIdx.x;
    __shared__ float pws[48 * 258];
    __shared__ float xs[16][48];
    for (int it = 0; it < 48; ++it) {
        int idx = tid + it * 256;
        float v = pw[idx];
        int dd = idx / 48, k = idx - dd * 48;
        pws[k * 258 + dd] = v;
    }
    for (int idx = tid; idx < 16 * 48; idx += 256) {
        int li = idx / 48, k = idx - li * 48;
        int c = k >> 4, py = (k >> 2) & 3, px = k & 3;
        xs[li][k] = x[(size_t)(b * 3 + c) * 4096 + (lg * 4 + py) * 64 + li * 4 + px];
    }
    __syncthreads();
    float bv = pb[tid];
#pragma unroll 4
    for (int li = 0; li < 16; ++li) {
        float acc = bv;
#pragma unroll
        for (int k = 0; k < 48; ++k) acc += xs[li][k] * pws[k * 258 + tid];
        h[((size_t)(b * 256 + lg * 16 + li)) * 256 + tid] = acc;
    }
}

// ---------------- time embedding ----------------
__global__ void time_embed(const int* __restrict__ t, const float* __restrict__ tw1,
                           const float* __restrict__ tb1, const float* __restrict__ tw2,
                           const float* __restrict__ tb2, float* __restrict__ te) {
    int b = blockIdx.x, j = threadIdx.x;
    __shared__ float s0[256], s1[256];
    float tv = (float)t[b];
    if (j < 128) {
        float f = expf((float)j * (-9.210340371976184f / 127.f));
        float a = tv * f;
        s0[j] = sinf(a);
        s0[j + 128] = cosf(a);
    }
    __syncthreads();
    float acc = tb1[j];
    for (int k = 0; k < 256; ++k) acc += s0[k] * tw1[j * 256 + k];
    s1[j] = acc / (1.f + expf(-acc));
    __syncthreads();
    float acc2 = tb2[j];
    for (int k = 0; k < 256; ++k) acc2 += s1[k] * tw2[j * 256 + k];
    te[b * 256 + j] = acc2;
}

// ---------------- layernorm ----------------
template <typename TO>
__global__ void ln_kernel(const float* __restrict__ h, const float* __restrict__ te,
                          const float* __restrict__ g, const float* __restrict__ bta,
                          TO* __restrict__ out) {
    int row = blockIdx.x;
    int b = row >> 8;
    int d = threadIdx.x;
    float v = h[(size_t)row * 256 + d] + (te ? te[b * 256 + d] : 0.f);
    float s = v, s2 = v * v;
#pragma unroll
    for (int o = 32; o; o >>= 1) {
        s += __shfl_down(s, o, 64);
        s2 += __shfl_down(s2, o, 64);
    }
    __shared__ float ws[4], ws2[4];
    int wid = threadIdx.x >> 6, lane = threadIdx.x & 63;
    if (lane == 0) { ws[wid] = s; ws2[wid] = s2; }
    __syncthreads();
    float mu = (ws[0] + ws[1] + ws[2] + ws[3]) * (1.f / 256.f);
    float m2 = (ws2[0] + ws2[1] + ws2[2] + ws2[3]) * (1.f / 256.f);
    float var = m2 - mu * mu;
    stf(&out[(size_t)row * 256 + d], (v - mu) * rsqrtf(var + 1e-5f) * g[d] + bta[d]);
}

// ---------------- bf16 MFMA GEMM (bf16 weights) ----------------
template <int BM, int BN, int WM, int WN, int FM, int FN, int ACT, bool ADD,
          bool HASBIAS, int AMODE, bool OBF>
__global__ __launch_bounds__(256) void gemm_mfma(
    const void* __restrict__ Ap, const __hip_bfloat16* __restrict__ W,
    const float* __restrict__ bias, void* __restrict__ Cp,
    int M, int N, int K, int lda,
    const void* __restrict__ A2p, const __hip_bfloat16* __restrict__ W2,
    const float* __restrict__ bias2, int nsplit)
{
    constexpr int LDP = 40;
    __shared__ __align__(16) short As[BM * LDP];
    __shared__ __align__(16) short Ws[BN * LDP];
    int tid = threadIdx.x;
    int lane = tid & 63;
    int w = tid >> 6;
    int wm, wn;
    if (WN == 1) { wm = w; wn = 0; } else { wm = w >> 1; wn = w & 1; }
    int m0 = blockIdx.x * BM;
    int n0 = blockIdx.y * BN;
    int wn0 = n0;
    if (nsplit > 0 && n0 >= nsplit) { Ap = A2p; W = W2; bias = bias2; wn0 = n0 - nsplit; }

    f32x4 acc[FM][FN];
#pragma unroll
    for (int i = 0; i < FM; ++i)
#pragma unroll
        for (int j = 0; j < FN; ++j) acc[i][j] = (f32x4){0.f, 0.f, 0.f, 0.f};

    for (int k0 = 0; k0 < K; k0 += 32) {
        if (AMODE == 0) {
            for (int idx = tid; idx < BM * 4; idx += 256) {
                int row = idx >> 2, qc = idx & 3;
                const __hip_bfloat16* g = (const __hip_bfloat16*)Ap +
                    (size_t)(m0 + row) * lda + k0 + qc * 8;
                *(bf16x8*)&As[row * LDP + qc * 8] = *(const bf16x8*)g;
            }
        } else if (AMODE == 1) {
            for (int idx = tid; idx < BM * 4; idx += 256) {
                int row = idx >> 2, qc = idx & 3;
                const float* g = (const float*)Ap + (size_t)(m0 + row) * lda + k0 + qc * 8;
                float4 v0 = *(const float4*)g;
                float4 v1 = *(const float4*)(g + 4);
                union { bf16x8 v; short s[8]; } u8;
                u8.s[0] = f2bf(v0.x); u8.s[1] = f2bf(v0.y); u8.s[2] = f2bf(v0.z); u8.s[3] = f2bf(v0.w);
                u8.s[4] = f2bf(v1.x); u8.s[5] = f2bf(v1.y); u8.s[6] = f2bf(v1.z); u8.s[7] = f2bf(v1.w);
                *(bf16x8*)&As[row * LDP + qc * 8] = u8.v;
            }
        } else {
            for (int idx = tid; idx < BM * 4; idx += 256) {
                int row = idx >> 2, qc = idx & 3;
                size_t rb = (size_t)(m0 + row) * 1024 + k0 + qc * 8;
                union { bf16x8 v; short s[8]; } uf, ub, uz, r;
                uf.v = *(const bf16x8*)((const __hip_bfloat16*)Ap + rb);
                ub.v = *(const bf16x8*)((const __hip_bfloat16*)Ap + rb + 512);
                uz.v = *(const bf16x8*)((const __hip_bfloat16*)A2p + rb + 512);
#pragma unroll
                for (int e = 0; e < 8; ++e) {
                    float z = bf2f_s(uz.s[e]);
                    float sg = z / (1.f + __expf(-z));
                    r.s[e] = f2bf((bf2f_s(uf.s[e]) + bf2f_s(ub.s[e])) * sg);
                }
                *(bf16x8*)&As[row * LDP + qc * 8] = r.v;
            }
        }
        for (int idx = tid; idx < BN * 4; idx += 256) {
            int row = idx >> 2, qc = idx & 3;
            const __hip_bfloat16* g = W + (size_t)(wn0 + row) * K + k0 + qc * 8;
            *(bf16x8*)&Ws[row * LDP + qc * 8] = *(const bf16x8*)g;
        }
        __syncthreads();
        int kg = lane >> 4, r = lane & 15;
        bf16x8 af[FM], bfr[FN];
#pragma unroll
        for (int i = 0; i < FM; ++i)
            af[i] = *(const bf16x8*)&As[(wm * FM * 16 + i * 16 + r) * LDP + kg * 8];
#pragma unroll
        for (int j = 0; j < FN; ++j)
            bfr[j] = *(const bf16x8*)&Ws[(wn * FN * 16 + j * 16 + r) * LDP + kg * 8];
#pragma unroll
        for (int i = 0; i < FM; ++i)
#pragma unroll
            for (int j = 0; j < FN; ++j)
                acc[i][j] = __builtin_amdgcn_mfma_f32_16x16x32_bf16(af[i], bfr[j], acc[i][j], 0, 0, 0);
        __syncthreads();
    }
    int r = lane & 15, qg = lane >> 4;
#pragma unroll
    for (int i = 0; i < FM; ++i) {
#pragma unroll
        for (int j = 0; j < FN; ++j) {
            int col = n0 + wn * FN * 16 + j * 16 + r;
            int colw = wn0 + wn * FN * 16 + j * 16 + r;
            float bv = HASBIAS ? bias[colw] : 0.f;
#pragma unroll
            for (int q = 0; q < 4; ++q) {
                int rowm = m0 + wm * FM * 16 + i * 16 + qg * 4 + q;
                float v = acc[i][j][q] + bv;
                if (ACT == 1) v = (v > 20.f) ? v : log1pf(__expf(v));
                size_t o = (size_t)rowm * N + col;
                if (OBF) ((__hip_bfloat16*)Cp)[o] = __float2bfloat16(v);
                else if (ADD) ((float*)Cp)[o] += v;
                else ((float*)Cp)[o] = v;
            }
        }
    }
}

// ---------------- fp32 GEMM head (fused unpatchify epilogue) ----------------
template <bool UNPATCH>
__global__ __launch_bounds__(256) void gemm_nt(const float* __restrict__ A,
                                               const float* __restrict__ W,
                                               const float* __restrict__ bias,
                                               float* __restrict__ C,
                                               int M, int N, int K, int lda) {
    __shared__ float Asm[16][65];
    __shared__ float Wsm[16][65];
    int tx = threadIdx.x & 15, ty = threadIdx.x >> 4;
    int m0 = blockIdx.x * 64, n0 = blockIdx.y * 64;
    float acc[4][4] = {};
    for (int k0 = 0; k0 < K; k0 += 16) {
#pragma unroll
        for (int i = 0; i < 4; ++i) {
            int idx = threadIdx.x + i * 256;
            int rr = idx >> 4, cc = idx & 15;
            Asm[cc][rr] = A[(size_t)(m0 + rr) * lda + k0 + cc];
            int n = n0 + rr;
            Wsm[cc][rr] = (n < N) ? W[(size_t)n * K + k0 + cc] : 0.f;
        }
        __syncthreads();
#pragma unroll
        for (int k = 0; k < 16; ++k) {
            float av[4], wv[4];
#pragma unroll
            for (int i = 0; i < 4; ++i) av[i] = Asm[k][ty * 4 + i];
#pragma unroll
            for (int j = 0; j < 4; ++j) wv[j] = Wsm[k][tx * 4 + j];
#pragma unroll
            for (int i = 0; i < 4; ++i)
#pragma unroll
                for (int j = 0; j < 4; ++j) acc[i][j] += av[i] * wv[j];
        }
        __syncthreads();
    }
#pragma unroll
    for (int i = 0; i < 4; ++i) {
        int m = m0 + ty * 4 + i;
#pragma unroll
        for (int j = 0; j < 4; ++j) {
            int n = n0 + tx * 4 + j;
            if (n < N) {
                float v = acc[i][j] + bias[n];
                if (UNPATCH) {
                    int b = m >> 8, l = m & 255;
                    int c = n >> 4;
                    int hy = ((l >> 4) << 2) + ((n >> 2) & 3);
                    int wx = ((l & 15) << 2) + (n & 3);
                    C[(size_t)(b * 3 + c) * 4096 + hy * 64 + wx] = v;
                } else {
                    C[(size_t)m * N + n] = v;
                }
            }
        }
    }
}

// ---------------- causal depthwise conv (k=4) + silu ----------------
__global__ __launch_bounds__(256) void conv_silu(
    const __hip_bfloat16* __restrict__ xz, const float* __restrict__ cw,
    const float* __restrict__ cb, __hip_bfloat16* __restrict__ u) {
    int g = blockIdx.x * 4 + (threadIdx.x >> 6);
    int lane = threadIdx.x & 63;
    int l = g & 255;
    int d0 = lane * 8;
    const __hip_bfloat16* base = xz + (size_t)g * 1024 + d0;
    union { bf16x8 v; short s[8]; } t0, t1, t2, t3, r;
    bf16x8 zz = {};
    t3.v = *(const bf16x8*)base;
    t2.v = (l >= 1) ? *(const bf16x8*)(base - 1024) : zz;
    t1.v = (l >= 2) ? *(const bf16x8*)(base - 2048) : zz;
    t0.v = (l >= 3) ? *(const bf16x8*)(base - 3072) : zz;
#pragma unroll
    for (int e = 0; e < 8; ++e) {
        int d = d0 + e;
        const float4 wv = *(const float4*)(cw + d * 4);
        float acc = cb[d] + bf2f_s(t0.s[e]) * wv.x + bf2f_s(t1.s[e]) * wv.y +
                    bf2f_s(t2.s[e]) * wv.z + bf2f_s(t3.s[e]) * wv.w;
        r.s[e] = f2bf(acc / (1.f + __expf(-acc)));
    }
    *(bf16x8*)(u + (size_t)g * 512 + d0) = r.v;
}

// ================= fused SSM scan v8: dt-MFMA + LDS-resident recurrence =================
// 512 blocks (XCD-swizzled), 512 threads = 16 chunks x 32 channels.
// Per block: stage u[256][32] + pf2 B/C + dtp/dtw; compute dt = softplus(dtp@dtw^T+b)
// via 32 MFMAs in-kernel; recurrence reads only LDS; y written ONCE (fast path).
// LDS exactly 80 KB (dtp/dtw staging aliased with PF prefix buffer) -> 2 blocks/CU.
__global__ __launch_bounds__(512) void scan_fused(
    const __hip_bfloat16* __restrict__ u, const float* __restrict__ pf2,
    const __hip_bfloat16* __restrict__ dtwF, const __hip_bfloat16* __restrict__ dtwB,
    const float* __restrict__ dtbF, const float* __restrict__ dtbB,
    const float* __restrict__ Alog_f, const float* __restrict__ Alog_b,
    const float* __restrict__ Dv_f, const float* __restrict__ Dv_b,
    __hip_bfloat16* __restrict__ y2)
{
    int blk = blockIdx.x;
    int c8 = blk & 7, idxb = blk >> 3;
    int bd = c8 + 8 * (idxb & 3);      // XCD swizzle: same bd -> same XCD
    int dg = idxb >> 2;
    int dir = bd & 1, b = bd >> 1;
    int tid = threadIdx.x;
    int dl = tid & 31, cc = tid >> 5;
    int d0 = dg * 32;
    int d = d0 + dl;
    int poff = dir ? 64 : 0;
    int doff = dir ? 512 : 0;
    const float* Alog = dir ? Alog_b : Alog_f;
    float Dval = (dir ? Dv_b : Dv_f)[d];
    const __hip_bfloat16* dtw = dir ? dtwB : dtwF;
    const float* dtb = dir ? dtbB : dtbF;

    __shared__ __align__(16) short Ush[256 * 32];    // 16 KB  (raw row order)
    __shared__ __align__(16) short DTs[256 * 32];    // 16 KB  (raw row order)
    __shared__ __align__(16) short Bsm[256 * 16];    // 8 KB   (scan order)
    __shared__ __align__(16) short Csm[256 * 16];    // 8 KB
    __shared__ __align__(16) unsigned PFR[8192];     // 32 KB: dtp[256][40]+dtw[32][40], then PF
    short* dtpL = (short*)PFR;                       // 20480 B
    short* dtwL = (short*)PFR + 10240;               // 2560 B

    // ---- staging ----
    for (int idx = tid; idx < 1024; idx += 512) {    // u
        int row = idx >> 2, q = idx & 3;
        *(bf16x8*)&Ush[row * 32 + q * 8] =
            *(const bf16x8*)(u + ((size_t)(b * 256 + row)) * 512 + d0 + q * 8);
    }
    for (int idx = tid; idx < 4096; idx += 512) {    // B, C (scan order)
        int i = idx >> 4, s = idx & 15;
        int tt = dir ? 255 - i : i;
        const float* pr = pf2 + ((size_t)b * 256 + tt) * 128 + poff;
        Bsm[i * 16 + s] = f2bf(pr[32 + s]);
        Csm[i * 16 + s] = f2bf(pr[48 + s]);
    }
    for (int idx = tid; idx < 2048; idx += 512) {    // dtp (raw row order)
        int row = idx >> 3, q = idx & 7;
        float4 v = *(const float4*)(pf2 + ((size_t)(b * 256 + row)) * 128 + poff + q * 4);
        bf16x4 r4; r4[0] = f2bf(v.x); r4[1] = f2bf(v.y); r4[2] = f2bf(v.z); r4[3] = f2bf(v.w);
        *(bf16x4*)&dtpL[row * 40 + q * 4] = r4;
    }
    if (tid < 128) {                                 // dtw rows d0..d0+31
        int row = tid >> 2, q = tid & 3;
        *(bf16x8*)&dtwL[row * 40 + q * 8] =
            *(const bf16x8*)(dtw + (size_t)(d0 + row) * 32 + q * 8);
    }
    // ---- A-structure check ----
    float A0c;
    int okl = 1;
    {
        const float* ap = Alog + d * 16;
        float A0 = -__expf(ap[0]);
        A0c = A0 * 1.44269504f;
#pragma unroll
        for (int s = 1; s < 16; ++s) {
            float As_ = -__expf(ap[s]);
            okl = okl && (fabsf(As_ - (float)(s + 1) * A0) <= 1e-3f * (float)(s + 1));
        }
    }
    bool fast = __syncthreads_and(okl) != 0;   // barrier #1: staging visible, vote

    // ---- dt via MFMA: wave w covers row-tiles t=2w,2w+1, col-tiles ct=0,1 ----
    {
        int w = tid >> 6, lane = tid & 63;
        int r = lane & 15, kg = lane >> 4;
#pragma unroll
        for (int p = 0; p < 4; ++p) {
            int t = 2 * w + (p >> 1);
            int ct = p & 1;
            bf16x8 af = *(const bf16x8*)&dtpL[(t * 16 + r) * 40 + kg * 8];
            bf16x8 bfr = *(const bf16x8*)&dtwL[(ct * 16 + r) * 40 + kg * 8];
            f32x4 acc = (f32x4){0.f, 0.f, 0.f, 0.f};
            acc = __builtin_amdgcn_mfma_f32_16x16x32_bf16(af, bfr, acc, 0, 0, 0);
            int colL = ct * 16 + r;
            float bvv = dtb[d0 + colL];
#pragma unroll
            for (int q = 0; q < 4; ++q) {
                int rowl = t * 16 + kg * 4 + q;     // C: row=(lane>>4)*4+reg, col=lane&15
                float vdt = acc[q] + bvv;
                vdt = (vdt > 20.f) ? vdt : log1pf(__expf(vdt));
                DTs[rowl * 32 + colL] = f2bf(vdt);
            }
        }
    }
    __syncthreads();   // barrier #2: DT visible; dtp/dtw dead (PFR reusable)

    int i0 = cc * 16;
    int row0 = b * 256 + (dir ? 255 - i0 : i0);
    int stpE = dir ? -1 : 1;
    int dstep = stpE * 1024;
    __hip_bfloat16* yp0 = y2 + (size_t)row0 * 1024 + doff + d;

    if (fast) {
        float h[16], yl[16], v1k[16];
#pragma unroll
        for (int s = 0; s < 16; ++s) h[s] = 0.f;
        // ---- Pass A: LDS-only local scan ----
#pragma unroll
        for (int k = 0; k < 16; ++k) {
            int i = i0 + k;
            int tt = dir ? 255 - i : i;
            float dt_ = bf2f_s(DTs[tt * 32 + dl]);
            float uv  = bf2f_s(Ush[tt * 32 + dl]);
            float du = dt_ * uv;
            float Bv[16], Cv[16];
            unpack16(&Bsm[i * 16], Bv);
            unpack16(&Csm[i * 16], Cv);
            float v1 = exp2f(dt_ * A0c);
            v1k[k] = v1;
            float yv = uv * Dval;
            float dec = v1;
#pragma unroll
            for (int s = 0; s < 16; ++s) {
                h[s] = dec * h[s] + du * Bv[s];
                yv = fmaf(Cv[s], h[s], yv);
                dec *= v1;
            }
            yl[k] = yv;
        }
        float W = v1k[0];
#pragma unroll
        for (int k = 1; k < 16; ++k) W *= v1k[k];
        float pw = 1.f;
#pragma unroll
        for (int s = 0; s < 16; ++s) {
            pw *= W;
            unsigned wrd = (unsigned)(unsigned short)f2bf(pw) |
                           ((unsigned)(unsigned short)f2bf(h[s]) << 16);
            PFR[(s * 16 + cc) * 32 + dl] = wrd;
        }
        __syncthreads();   // barrier #3
        {
            int s2 = tid >> 5, dl2 = tid & 31;
            float hh = 0.f;
#pragma unroll
            for (int c2 = 0; c2 < 16; ++c2) {
                int idx = (s2 * 16 + c2) * 32 + dl2;
                unsigned wv = PFR[idx];
                float pv = __uint_as_float(wv << 16);
                float fv = __uint_as_float(wv & 0xFFFF0000u);
                ((float*)PFR)[idx] = hh;
                hh = fv + pv * hh;
            }
        }
        __syncthreads();   // barrier #4
        float q[16];
#pragma unroll
        for (int s = 0; s < 16; ++s) q[s] = ((float*)PFR)[(s * 16 + cc) * 32 + dl];
        float w1 = 1.f;
#pragma unroll
        for (int k = 0; k < 16; ++k) {
            w1 *= v1k[k];
            float Cv[16];
            unpack16(&Csm[(i0 + k) * 16], Cv);
            float acc = Cv[15] * q[15];
#pragma unroll
            for (int s = 14; s >= 0; --s) acc = acc * w1 + Cv[s] * q[s];
            yp0[k * dstep] = __float2bfloat16(yl[k] + acc * w1);
        }
    } else {
        // ---- generic fallback (correctness path) ----
        float A2[16];
        {
            const float* ap = Alog + d * 16;
#pragma unroll
            for (int s = 0; s < 16; ++s) A2[s] = -__expf(ap[s]) * 1.44269504f;
        }
        float h[16];
#pragma unroll
        for (int s = 0; s < 16; ++s) h[s] = 0.f;
        float S = 0.f;
        {
            __hip_bfloat16* yp = yp0;
#pragma unroll
            for (int k = 0; k < 16; ++k) {
                int i = i0 + k;
                int tt = dir ? 255 - i : i;
                float dt_ = bf2f_s(DTs[tt * 32 + dl]);
                float uv  = bf2f_s(Ush[tt * 32 + dl]);
                S += dt_;
                float du = dt_ * uv;
                float Bv[16], Cv[16];
                unpack16(&Bsm[i * 16], Bv);
                unpack16(&Csm[i * 16], Cv);
                float yv = uv * Dval;
#pragma unroll
                for (int s = 0; s < 16; ++s) {
                    h[s] = exp2f(dt_ * A2[s]) * h[s] + du * Bv[s];
                    yv = fmaf(Cv[s], h[s], yv);
                }
                *yp = __float2bfloat16(yv); yp += dstep;
            }
        }
#pragma unroll
        for (int s = 0; s < 16; ++s) {
            float Pv = exp2f(A2[s] * S);
            unsigned wrd = (unsigned)(unsigned short)f2bf(Pv) |
                           ((unsigned)(unsigned short)f2bf(h[s]) << 16);
            PFR[(s * 16 + cc) * 32 + dl] = wrd;
        }
        __syncthreads();
        {
            int s2 = tid >> 5, dl2 = tid & 31;
            float hh = 0.f;
#pragma unroll
            for (int c2 = 0; c2 < 16; ++c2) {
                int idx = (s2 * 16 + c2) * 32 + dl2;
                unsigned wv = PFR[idx];
                float pv = __uint_as_float(wv << 16);
                float fv = __uint_as_float(wv & 0xFFFF0000u);
                ((float*)PFR)[idx] = hh;
                hh = fv + pv * hh;
            }
        }
        __syncthreads();
        float q[16];
#pragma unroll
        for (int s = 0; s < 16; ++s) q[s] = ((float*)PFR)[(s * 16 + cc) * 32 + dl];
        __hip_bfloat16* yp = yp0;
        float S2 = 0.f;
#pragma unroll
        for (int k = 0; k < 16; ++k) {
            int i = i0 + k;
            int tt = dir ? 255 - i : i;
            float dt_ = bf2f_s(DTs[tt * 32 + dl]);
            S2 += dt_;
            float Cv[16];
            unpack16(&Csm[i * 16], Cv);
            float corr = 0.f;
#pragma unroll
            for (int s = 0; s < 16; ++s) corr += Cv[s] * q[s] * exp2f(A2[s] * S2);
            float ycur = __bfloat162float(*yp);
            *yp = __float2bfloat16(ycur + corr);
            yp += dstep;
        }
    }
}

extern "C" void kernel_launch(void* const* d_in, const int* in_sizes, int n_in,
                              void* d_out, int out_size, void* d_ws, size_t ws_size,
                              hipStream_t stream) {
    const float* x        = (const float*)d_in[0];
    const int*   t        = (const int*)d_in[1];
    const float* patch_w  = (const float*)d_in[2];
    const float* patch_b  = (const float*)d_in[3];
    const float* tw1      = (const float*)d_in[4];
    const float* tb1      = (const float*)d_in[5];
    const float* tw2      = (const float*)d_in[6];
    const float* tb2      = (const float*)d_in[7];
    const float* norm_g   = (const float*)d_in[8];
    const float* norm_b   = (const float*)d_in[9];
    const float* inproj_w = (const float*)d_in[10];
    const float* conv_w   = (const float*)d_in[11];
    const float* conv_b   = (const float*)d_in[12];
    const float* Alog_f   = (const float*)d_in[13];
    const float* D_f      = (const float*)d_in[14];
    const float* xproj_f  = (const float*)d_in[15];
    const float* dtw_f    = (const float*)d_in[16];
    const float* dtb_f    = (const float*)d_in[17];
    const float* Alog_bk  = (const float*)d_in[18];
    const float* D_bk     = (const float*)d_in[19];
    const float* xproj_bk = (const float*)d_in[20];
    const float* dtw_bk   = (const float*)d_in[21];
    const float* dtb_bk   = (const float*)d_in[22];
    const float* outproj_w= (const float*)d_in[23];
    const float* fng      = (const float*)d_in[24];
    const float* fnb      = (const float*)d_in[25];
    const float* fin_w    = (const float*)d_in[26];
    const float* fin_b    = (const float*)d_in[27];
    float* out = (float*)d_out;

    char* base = (char*)d_ws;
    float*          te  = (float*)base;                                   // 16 KB
    float*          h   = (float*)(base + (16UL << 10));                  // 4 MB
    __hip_bfloat16* hn  = (__hip_bfloat16*)(base + (16UL << 10) + (4UL << 20));   // 2 MB
    __hip_bfloat16* xz  = (__hip_bfloat16*)((char*)hn + (2UL << 20));     // 8 MB
    __hip_bfloat16* uu  = (__hip_bfloat16*)((char*)xz + (8UL << 20));     // 4 MB
    float*          pf2 = (float*)((char*)uu + (4UL << 20));              // 2 MB
    float*          hnf = (float*)((char*)pf2 + (2UL << 20));             // 4 MB (was dt2)
    __hip_bfloat16* y2  = (__hip_bfloat16*)((char*)hnf + (8UL << 20));    // 8 MB
    __hip_bfloat16* wbf = (__hip_bfloat16*)((char*)y2 + (8UL << 20));     // 4 MB

    __hip_bfloat16* w_in  = wbf;
    __hip_bfloat16* w_xf  = wbf + 1048576;
    __hip_bfloat16* w_xb  = wbf + 1179648;
    __hip_bfloat16* w_dtf = wbf + 1310720;
    __hip_bfloat16* w_dtb = wbf + 1376256;
    __hip_bfloat16* w_out = wbf + 1441792;

    const int M = BB * LL;                // 4096

    cvt_w<<<1920, 256, 0, stream>>>(inproj_w, xproj_f, xproj_bk, dtw_f, dtw_bk,
                                    outproj_w, wbf);
    patch_embed<<<256, 256, 0, stream>>>(x, patch_w, patch_b, h);
    time_embed<<<BB, 256, 0, stream>>>(t, tw1, tb1, tw2, tb2, te);

    for (int i = 0; i < 4; ++i) {
        ln_kernel<__hip_bfloat16><<<M, 256, 0, stream>>>(
            h, te, norm_g + i * 256, norm_b + i * 256, hn);
        gemm_mfma<128, 128, 2, 2, 4, 4, 0, false, false, 0, true><<<dim3(32, 8), 256, 0, stream>>>(
            hn, w_in + (size_t)i * 262144, nullptr, xz, M, 1024, 256, 256,
            nullptr, nullptr, nullptr, 0);
        conv_silu<<<1024, 256, 0, stream>>>(xz, conv_w + i * 2048, conv_b + i * 512, uu);
        gemm_mfma<32, 64, 2, 2, 1, 2, 0, false, false, 0, false><<<dim3(128, 2), 256, 0, stream>>>(
            uu, w_xf + (size_t)i * 32768, nullptr, pf2, M, 128, 512, 512,
            uu, w_xb + (size_t)i * 32768, nullptr, 64);
        scan_fused<<<512, 512, 0, stream>>>(uu, pf2,
            w_dtf + (size_t)i * 16384, w_dtb + (size_t)i * 16384,
            dtb_f + i * 512, dtb_bk + i * 512,
            Alog_f + (size_t)i * 8192, Alog_bk + (size_t)i * 8192,
            D_f + i * 512, D_bk + i * 512, y2);
        gemm_mfma<64, 64, 4, 1, 1, 4, 0, true, false, 2, false><<<dim3(64, 4), 256, 0, stream>>>(
            y2, w_out + (size_t)i * 131072, nullptr, h, M, 256, 512, 1024,
            xz, nullptr, nullptr, 0);
    }

    ln_kernel<float><<<M, 256, 0, stream>>>(h, nullptr, fng, fnb, hnf);
    gemm_nt<true><<<dim3(64, 1), 256, 0, stream>>>(
        hnf, fin_w, fin_b, out, M, 48, 256, 256);
}